// Round 8
// baseline (761.558 us; speedup 1.0000x reference)
//
#include <hip/hip_runtime.h>

typedef unsigned short u16;
typedef unsigned int u32;
typedef __attribute__((ext_vector_type(4))) int i32x4;
typedef __attribute__((ext_vector_type(16))) int i32x16;

#define TT 16
#define Z16 {0, 0, 0, 0, 0, 0, 0, 0, 0, 0, 0, 0, 0, 0, 0, 0}

// ---------------------------------------------------------------------------
// f64 LIF scan (soft reset, THETA=1). R2..R7: absmax=0.0 => order-free,
// margins >> f64 noise.
// ---------------------------------------------------------------------------
__device__ __forceinline__ u32 scan_spike(const double* acc) {
  double u = 0.0;
  u32 m = 0;
#pragma unroll
  for (int t = 0; t < TT; ++t) {
    u += acc[t];
    if (u >= 1.0) { m |= (1u << t); u -= 1.0; }
  }
  return m;
}

__device__ __forceinline__ long long shfl_xor64(long long v, int m) {
  int lo = __shfl_xor((int)(v & 0xffffffffLL), m);
  int hi = __shfl_xor((int)(v >> 32), m);
  return ((long long)hi << 32) | (u32)lo;
}

// ---------------------------------------------------------------------------
// Layer 1: conv3x3 pad1 Cin=1, LDS-staged, 4 oc/thread (R5-verbatim, proven).
// ---------------------------------------------------------------------------
__global__ __launch_bounds__(224) void conv1_lds(
    const float* __restrict__ x, const float* __restrict__ w,
    const float* __restrict__ b, u16* __restrict__ out) {
  __shared__ float xt[3][30][18];
  __shared__ double wl[32][9];

  int blk = blockIdx.x;
  int y = blk % 28, n = blk / 28;
  int tid = threadIdx.x;

  for (int i = tid; i < 288; i += 224) wl[i / 9][i % 9] = (double)w[i];
  for (int i = tid; i < 3 * 30 * 16; i += 224) {
    int r = i / 480; int rem = i % 480;
    int col = rem / 16; int t = rem % 16;
    int yi = y - 1 + r, xi = col - 1;
    float v = 0.0f;
    if ((unsigned)yi < 28u && (unsigned)xi < 28u)
      v = x[((size_t)(n * 28 + yi) * 28 + xi) * 16 + t];
    xt[r][col][t] = v;
  }
  __syncthreads();

  int xx = tid % 28, ocg = tid / 28, oc0 = ocg * 4;

  double acc[4][TT];
#pragma unroll
  for (int j = 0; j < 4; ++j) {
    double bv = (double)b[oc0 + j];
#pragma unroll
    for (int t = 0; t < TT; ++t) acc[j][t] = bv;
  }

#pragma unroll
  for (int ky = 0; ky < 3; ++ky)
#pragma unroll
    for (int kx = 0; kx < 3; ++kx) {
      int ko = ky * 3 + kx;
      double w0 = wl[oc0][ko], w1 = wl[oc0 + 1][ko];
      double w2 = wl[oc0 + 2][ko], w3 = wl[oc0 + 3][ko];
#pragma unroll
      for (int t = 0; t < TT; ++t) {
        double xv = (double)xt[ky][xx + kx][t];
        acc[0][t] = fma(w0, xv, acc[0][t]);
        acc[1][t] = fma(w1, xv, acc[1][t]);
        acc[2][t] = fma(w2, xv, acc[2][t]);
        acc[3][t] = fma(w3, xv, acc[3][t]);
      }
    }

#pragma unroll
  for (int j = 0; j < 4; ++j) {
    u32 mo = scan_spike(acc[j]);
    out[((size_t)(n * 32 + oc0 + j) * 28 + y) * 28 + xx] = (u16)mo;
  }
}

// ---------------------------------------------------------------------------
// Digit prep in MFMA B-frag order for the 32ch 3x3 convs (R4-verbatim).
// ---------------------------------------------------------------------------
__global__ void prep_digits_frag(const float* __restrict__ w,
                                 signed char* __restrict__ Wd) {
  int tap = blockIdx.x;    // 9
  int lane = threadIdx.x;  // 64
  int oc = lane & 31, kh = lane >> 5;
  for (int j = 0; j < 16; ++j) {
    int c = kh * 16 + j;
    double xv = ldexp((double)w[((size_t)(oc * 32 + c)) * 9 + tap], 45);
    long long X = (long long)rint(xv);
    for (int p = 0; p < 6; ++p) {
      int d = (int)((X + 128) & 255) - 128;
      Wd[((size_t)((p * 9 + tap) * 64 + lane)) * 16 + j] = (signed char)d;
      X = (X - (long long)d) >> 8;
    }
  }
}

// ---------------------------------------------------------------------------
// Expand packed u16 masks -> T[nloc][30][30][16][32] bytes (R4-verbatim).
// ---------------------------------------------------------------------------
__global__ __launch_bounds__(256) void expand_masks(
    const u16* __restrict__ s, signed char* __restrict__ T, int nbase) {
  int site = blockIdx.x * 8 + (threadIdx.x >> 5);
  int gl = threadIdx.x & 31;
  int x = site % 28; int t1 = site / 28;
  int y = t1 % 28;   int nloc = t1 / 28;

  u32 v = (u32)s[(((size_t)(nbase + nloc) * 32 + gl) * 28 + y) * 28 + x];
  const u32 MK[5] = {0x0000FFFFu, 0x00FF00FFu, 0x0F0F0F0Fu,
                     0x33333333u, 0x55555555u};
#pragma unroll
  for (int i = 0; i < 5; ++i) {
    int sh = 16 >> i;
    u32 mk = MK[i];
    u32 p = (u32)__shfl_xor((int)v, sh);
    v = ((gl & sh) == 0) ? ((v & mk) | ((p & mk) << sh))
                         : ((v & ~mk) | ((p & ~mk) >> sh));
  }
  if (gl < 16) {
    u32 dw[8];
#pragma unroll
    for (int d = 0; d < 8; ++d) {
      u32 nib = (v >> (4 * d)) & 0xFu;
      dw[d] = (nib * 0x00204081u) & 0x01010101u;
    }
    signed char* Tp =
        T + (((size_t)nloc * 30 + y + 1) * 30 + (x + 1)) * 512 + gl * 32;
    *(i32x4*)Tp = (i32x4){(int)dw[0], (int)dw[1], (int)dw[2], (int)dw[3]};
    *(i32x4*)(Tp + 16) = (i32x4){(int)dw[4], (int)dw[5], (int)dw[6], (int)dw[7]};
  }
}

// ---------------------------------------------------------------------------
// Integer epilogue for 32x32 i8 MFMA C-layout (R4-verbatim, proven).
// ---------------------------------------------------------------------------
template <bool WRITE_T, bool HAS_RES>
__device__ __forceinline__ void epi_i8(long long (&cc)[16], int h, int oc,
                                       int px_out, int y, int nloc, int n_g,
                                       const float* bias,
                                       const u16* __restrict__ res,
                                       signed char* __restrict__ Tout,
                                       u16* __restrict__ mout) {
  long long recv[8];
#pragma unroll
  for (int j = 0; j < 8; ++j) {
    long long send = h ? cc[j] : cc[8 + j];
    recv[j] = shfl_xor64(send, 32);
  }
  long long B45 = (long long)rint((double)bias[oc] * 35184372088832.0);
  u32 rm = 0;
  if (HAS_RES && px_out < 28)
    rm = res[(((size_t)n_g * 32 + oc) * 28 + y) * 28 + px_out];
  long long u = 0;
  u32 mo = 0;
  const long long TH = 1LL << 45;
#pragma unroll
  for (int t = 0; t < TT; ++t) {
    int lo = (t & 3) + 4 * (t >> 3);
    int sel = (t >> 2) & 1;
    long long own = h ? cc[8 + lo] : cc[lo];
    long long ut = (sel ^ h) ? recv[lo] : own;
    ut += B45 + (((rm >> t) & 1u) ? TH : 0);
    u += ut;
    if (u >= TH) { mo |= (1u << t); u -= TH; }
  }
  if (px_out < 28) {
    if (WRITE_T) {
      signed char* Tp =
          Tout + (((size_t)nloc * 30 + y + 1) * 30 + px_out + 1) * 512 + oc;
#pragma unroll
      for (int t = 0; t < TT; ++t)
        Tp[t * 32] = (signed char)((mo >> t) & 1u);
    } else {
      mout[(((size_t)n_g * 32 + oc) * 28 + y) * 28 + px_out] = (u16)mo;
    }
  }
}

// ---------------------------------------------------------------------------
// conv3x3 32->32 via exact i8 32x32x32 MFMA. R8: ONE 2-px tile per wave
// (grid x2), plane-PAIR accumulation: a_lo,a_hi per pair, combined in i32 as
// c_pair = a_lo + (a_hi<<8) (|a_p| <= 127*288 -> |c_pair| < 9.5e6, exact),
// i64 built once in epilogue: cc = c01 + (c23<<16) + (c45<<32) (exact int
// identity). K-loop i64 VALU (384 inst) -> 48 lshl_add_u32. No early return,
// no reference-selects (the R6/R7 spill-forcers). epi_i8 verbatim.
// ---------------------------------------------------------------------------
template <bool WRITE_T, bool HAS_RES>
__global__ __launch_bounds__(256, 2) void conv_i8(
    const signed char* __restrict__ Tin, const signed char* __restrict__ Wd,
    const float* __restrict__ bias, const u16* __restrict__ res,
    signed char* __restrict__ Tout, u16* __restrict__ mout, int nbase) {
  int tid = threadIdx.x;
  int blk = blockIdx.x;
  int xblk = blk & 3; int b2 = blk >> 2;
  int y = b2 % 28;    int nloc = b2 / 28;
  int lane = tid & 63, wid = tid >> 6;
  int h = lane >> 5, rowlane = lane & 31;
  int pxr = rowlane >> 4, tA = rowlane & 15;
  int pxb = xblk * 8 + wid * 2;  // 0..30; tiles >=28 discarded at store

  i32x4 A[9];
  const signed char* Tn = Tin + (size_t)nloc * (30 * 30 * 512);
#pragma unroll
  for (int ky = 0; ky < 3; ++ky)
#pragma unroll
    for (int kx = 0; kx < 3; ++kx) {
      int tap = ky * 3 + kx;
      int ypad = y + ky;
      int x0 = pxb + pxr + kx;
      if (x0 > 29) x0 = 29;  // only for discarded tiles
      A[tap] = *(const i32x4*)(Tn + ((size_t)(ypad * 30 + x0)) * 512 +
                               tA * 32 + h * 16);
    }

  i32x16 cpair[3];
#pragma unroll
  for (int pp = 0; pp < 3; ++pp) {
    i32x16 alo = Z16, ahi = Z16;
#pragma unroll
    for (int tap = 0; tap < 9; ++tap) {
      i32x4 Blo =
          *(const i32x4*)&Wd[((size_t)(((2 * pp) * 9 + tap) * 64 + lane)) * 16];
      i32x4 Bhi = *(const i32x4*)&Wd[((size_t)(((2 * pp + 1) * 9 + tap) * 64 +
                                               lane)) * 16];
      alo = __builtin_amdgcn_mfma_i32_32x32x32_i8(A[tap], Blo, alo, 0, 0, 0);
      ahi = __builtin_amdgcn_mfma_i32_32x32x32_i8(A[tap], Bhi, ahi, 0, 0, 0);
    }
#pragma unroll
    for (int r = 0; r < 16; ++r) cpair[pp][r] = alo[r] + (ahi[r] << 8);
  }

  long long cc[16];
#pragma unroll
  for (int r = 0; r < 16; ++r)
    cc[r] = (long long)cpair[0][r] + ((long long)cpair[1][r] << 16) +
            ((long long)cpair[2][r] << 32);

  epi_i8<WRITE_T, HAS_RES>(cc, h, rowlane, pxb + h, y, nloc, nbase + nloc,
                           bias, res, Tout, mout);
}

// ---------------------------------------------------------------------------
// 2x2 average pool + spike (R3-verbatim).
// ---------------------------------------------------------------------------
__global__ __launch_bounds__(256) void pool_spike(
    const u16* __restrict__ in, u16* __restrict__ out) {
  int idx = blockIdx.x * 256 + threadIdx.x;
  const int total = 128 * 32 * 14 * 14;
  if (idx >= total) return;
  int xx = idx % 14; int t1 = idx / 14;
  int yy = t1 % 14;  int t2 = t1 / 14;
  int c  = t2 % 32;  int n  = t2 / 32;

  const u16* base = in + ((size_t)(n * 32 + c) * 28 + yy * 2) * 28 + xx * 2;
  u32 m00 = base[0], m01 = base[1], m10 = base[28], m11 = base[29];

  double acc[TT];
#pragma unroll
  for (int t = 0; t < TT; ++t) {
    u32 s = ((m00 >> t) & 1u) + ((m01 >> t) & 1u) + ((m10 >> t) & 1u) +
            ((m11 >> t) & 1u);
    acc[t] = 0.25 * (double)s;
  }
  out[idx] = (u16)scan_spike(acc);
}

// ---------------------------------------------------------------------------
// conv1x1 on packed binary input + optional residual + spike (R3-verbatim).
// ---------------------------------------------------------------------------
template <int CIN>
__global__ __launch_bounds__(256) void conv1x1_spike(
    const u16* __restrict__ in, const float* __restrict__ w,
    const float* __restrict__ b, const u16* __restrict__ res,
    u16* __restrict__ out, int N, int Cout, int HW) {
  int idx = blockIdx.x * 256 + threadIdx.x;
  int total = N * Cout * HW;
  if (idx >= total) return;
  int p = idx % HW; int t1 = idx / HW;
  int o = t1 % Cout; int n = t1 / Cout;

  double acc[TT];
  double bv = (double)b[o];
#pragma unroll
  for (int t = 0; t < TT; ++t) acc[t] = bv;

  const u16* inp = in + (size_t)n * CIN * HW + p;
  const float* wo = w + (size_t)o * CIN;
#pragma unroll 4
  for (int c = 0; c < CIN; ++c) {
    u32 m = inp[c * HW];
    double wh = 0.5 * (double)wo[c];
#pragma unroll
    for (int t = 0; t < TT; ++t) {
      u32 hi = (m << (30 - t)) & 0x40000000u;
      acc[t] = fma(wh, __hiloint2double((int)hi, 0), acc[t]);
    }
  }
  if (res) {
    u32 m = res[idx];
#pragma unroll
    for (int t = 0; t < TT; ++t) acc[t] += ((m >> t) & 1u) ? 1.0 : 0.0;
  }
  out[idx] = (u16)scan_spike(acc);
}

// ---------------------------------------------------------------------------
// L6 digit prep (R6-verbatim, proven): w5 -> Wd5[(p*6+ch)][lane][16] B-frags.
// ---------------------------------------------------------------------------
__global__ void prep_digits5(const float* __restrict__ w,
                             signed char* __restrict__ Wd) {
  int ch = blockIdx.x;     // 6
  int lane = threadIdx.x;  // 64
  int ky = ch >> 1, kxb2 = ch & 1;
  int oc = lane & 31, kh = lane >> 5;
  int kx = kxb2 * 2 + kh;
  for (int j = 0; j < 16; ++j) {
    long long X = 0;
    if (oc < 16 && kx < 3) {
      double xv =
          ldexp((double)w[((size_t)(oc * 16 + j)) * 9 + ky * 3 + kx], 45);
      X = (long long)rint(xv);
    }
    for (int p = 0; p < 6; ++p) {
      int d = (int)((X + 128) & 255) - 128;
      Wd[((size_t)((p * 6 + ch) * 64 + lane)) * 16 + j] = (signed char)d;
      X = (X - (long long)d) >> 8;
    }
  }
}

// ---------------------------------------------------------------------------
// Expand s5 masks -> T5[n][16][16][16t][16c] (R6-verbatim, proven).
// ---------------------------------------------------------------------------
__global__ __launch_bounds__(256) void expand_t5(
    const u16* __restrict__ s, signed char* __restrict__ T) {
  int site = blockIdx.x * 8 + (threadIdx.x >> 5);  // 128*14*14
  int gl = threadIdx.x & 31;
  int x = site % 14; int t1 = site / 14;
  int y = t1 % 14;   int n = t1 / 14;

  u32 v = 0;
  if (gl < 16) v = (u32)s[(((size_t)n * 16 + gl) * 14 + y) * 14 + x];
  const u32 MK[5] = {0x0000FFFFu, 0x00FF00FFu, 0x0F0F0F0Fu,
                     0x33333333u, 0x55555555u};
#pragma unroll
  for (int i = 0; i < 5; ++i) {
    int sh = 16 >> i;
    u32 mk = MK[i];
    u32 p = (u32)__shfl_xor((int)v, sh);
    v = ((gl & sh) == 0) ? ((v & mk) | ((p & mk) << sh))
                         : ((v & ~mk) | ((p & ~mk) >> sh));
  }
  if (gl < 16) {
    u32 dw[4];
#pragma unroll
    for (int d = 0; d < 4; ++d) {
      u32 nib = (v >> (4 * d)) & 0xFu;
      dw[d] = (nib * 0x00204081u) & 0x01010101u;
    }
    *(i32x4*)(T + ((((size_t)(n * 16 + y + 1)) * 16 + x + 1) * 16 + gl) * 16) =
        (i32x4){(int)dw[0], (int)dw[1], (int)dw[2], (int)dw[3]};
  }
}

// ---------------------------------------------------------------------------
// L6: conv3x3 16->16 pad1 via exact i8 MFMA. R8: same pair-collapsed,
// no-early-return structure as conv_i8 (clamp-free reads stay inside the
// padded+slack allocation; kx==3 taps hit zero digits; tiles pxb>=14 are
// store-discarded). 6 K-chunks = (ky, kx-pair).
// ---------------------------------------------------------------------------
__global__ __launch_bounds__(256, 2) void conv5_i8(
    const signed char* __restrict__ T5, const signed char* __restrict__ Wd,
    const float* __restrict__ bias, u16* __restrict__ out) {
  int tid = threadIdx.x;
  int blk = blockIdx.x;  // 128*14*2
  int xblk = blk & 1; int b2 = blk >> 1;
  int y = b2 % 14, n = b2 / 14;
  int lane = tid & 63, wid = tid >> 6;
  int h = lane >> 5, rowlane = lane & 31;
  int pxr = rowlane >> 4, tA = rowlane & 15;
  int pxb = xblk * 8 + wid * 2;  // 0..14; pxb==14 discarded at store

  const signed char* Tn = T5 + (size_t)n * 65536;
  i32x4 A[6];
#pragma unroll
  for (int ch = 0; ch < 6; ++ch) {
    int ky = ch >> 1, kxb2 = ch & 1;
    int yp = y + ky;
    int x0 = pxb + pxr + kxb2 * 2 + h;  // <= 18: inside padded+slack alloc
    A[ch] = *(const i32x4*)(Tn + (((size_t)(yp * 16 + x0)) * 16 + tA) * 16);
  }

  i32x16 cpair[3];
#pragma unroll
  for (int pp = 0; pp < 3; ++pp) {
    i32x16 alo = Z16, ahi = Z16;
#pragma unroll
    for (int ch = 0; ch < 6; ++ch) {
      i32x4 Blo =
          *(const i32x4*)&Wd[((size_t)(((2 * pp) * 6 + ch) * 64 + lane)) * 16];
      i32x4 Bhi = *(const i32x4*)&Wd[((size_t)(((2 * pp + 1) * 6 + ch) * 64 +
                                               lane)) * 16];
      alo = __builtin_amdgcn_mfma_i32_32x32x32_i8(A[ch], Blo, alo, 0, 0, 0);
      ahi = __builtin_amdgcn_mfma_i32_32x32x32_i8(A[ch], Bhi, ahi, 0, 0, 0);
    }
#pragma unroll
    for (int r = 0; r < 16; ++r) cpair[pp][r] = alo[r] + (ahi[r] << 8);
  }

  long long cc[16];
#pragma unroll
  for (int r = 0; r < 16; ++r)
    cc[r] = (long long)cpair[0][r] + ((long long)cpair[1][r] << 16) +
            ((long long)cpair[2][r] << 32);

  long long recv[8];
#pragma unroll
  for (int j = 0; j < 8; ++j) {
    long long send = h ? cc[j] : cc[8 + j];
    recv[j] = shfl_xor64(send, 32);
  }
  const long long TH = 1LL << 45;
  long long B45 = (rowlane < 16)
                      ? (long long)rint((double)bias[rowlane] * 35184372088832.0)
                      : 0;
  long long u = 0;
  u32 mo = 0;
#pragma unroll
  for (int t = 0; t < TT; ++t) {
    int lo = (t & 3) + 4 * (t >> 3);
    int sel = (t >> 2) & 1;
    long long own = h ? cc[8 + lo] : cc[lo];
    long long ut = (sel ^ h) ? recv[lo] : own;
    ut += B45;
    u += ut;
    if (u >= TH) { mo |= (1u << t); u -= TH; }
  }
  int px_out = pxb + h;
  if (px_out < 14 && rowlane < 16)
    out[(((size_t)n * 16 + rowlane) * 14 + y) * 14 + px_out] = (u16)mo;
}

// ---------------------------------------------------------------------------
// Expand s7 masks -> T7[n][t][6272] bytes (R5-verbatim).
// ---------------------------------------------------------------------------
__global__ __launch_bounds__(256) void expand_t7(
    const u16* __restrict__ s, signed char* __restrict__ T) {
  int site = blockIdx.x * 8 + (threadIdx.x >> 5);
  int gl = threadIdx.x & 31;
  int fc = site % 196; int n = site / 196;

  u32 v = (u32)s[(size_t)n * 6272 + fc * 32 + gl];
  const u32 MK[5] = {0x0000FFFFu, 0x00FF00FFu, 0x0F0F0F0Fu,
                     0x33333333u, 0x55555555u};
#pragma unroll
  for (int i = 0; i < 5; ++i) {
    int sh = 16 >> i;
    u32 mk = MK[i];
    u32 p = (u32)__shfl_xor((int)v, sh);
    v = ((gl & sh) == 0) ? ((v & mk) | ((p & mk) << sh))
                         : ((v & ~mk) | ((p & ~mk) >> sh));
  }
  if (gl < 16) {
    u32 dw[8];
#pragma unroll
    for (int d = 0; d < 8; ++d) {
      u32 nib = (v >> (4 * d)) & 0xFu;
      dw[d] = (nib * 0x00204081u) & 0x01010101u;
    }
    signed char* Tp = T + ((size_t)n * 16 + gl) * 6272 + fc * 32;
    *(i32x4*)Tp = (i32x4){(int)dw[0], (int)dw[1], (int)dw[2], (int)dw[3]};
    *(i32x4*)(Tp + 16) = (i32x4){(int)dw[4], (int)dw[5], (int)dw[6], (int)dw[7]};
  }
}

// ---------------------------------------------------------------------------
// wf1 digit prep, B-frag order (R5-verbatim).
// ---------------------------------------------------------------------------
__global__ __launch_bounds__(256) void prep_dense_digits(
    const float* __restrict__ w, signed char* __restrict__ Wd) {
  int linear = blockIdx.x * 256 + threadIdx.x;  // < 301056
  int lane = linear & 63;
  int kc = (linear >> 6) % 196;
  int pg = (linear >> 6) / 196;
  int p = pg % 6, g = pg / 6;
  int col = lane & 31, kh = lane >> 5;
  int o = g * 32 + col, fb = kc * 32 + kh * 16;

  alignas(16) signed char dig[16];
#pragma unroll
  for (int j = 0; j < 16; ++j) {
    double xv = (double)w[(size_t)o * 6272 + fb + j] * 35184372088832.0;
    long long X = (long long)rint(xv);
    unsigned long long Y = (unsigned long long)(X + 0x808080808080LL);
    dig[j] = (signed char)(int)(((Y >> (8 * p)) & 255u) - 128);
  }
  *(i32x4*)(Wd + (size_t)linear * 16) = *(const i32x4*)dig;
}

// ---------------------------------------------------------------------------
// Dense 6272->128, phase A: 16-way K-split partial i8 GEMM (R6-verbatim).
// ---------------------------------------------------------------------------
__global__ __launch_bounds__(256) void dense1_part(
    const signed char* __restrict__ T7, const signed char* __restrict__ Wd,
    long long* __restrict__ Pbuf) {
  __shared__ long long red[3][64][16];
  int tid = threadIdx.x, lane = tid & 63, wid = tid >> 6;
  int bidx = blockIdx.x;
  int Mt = bidx & 63;
  int g = (bidx >> 6) & 3;
  int ks = bidx >> 8;
  int n0 = Mt * 2;
  int nl = (lane >> 4) & 1, tA = lane & 15, kh = lane >> 5;

  const signed char* Arow =
      T7 + ((size_t)(n0 + nl) * 16 + tA) * 6272 + kh * 16;
  const signed char* Bbase = Wd + (size_t)g * 6 * 196 * 1024 + lane * 16;

  int slot = ks * 4 + wid;
  int kc0 = slot * 12 + (slot < 4 ? slot : 4);
  int len = (slot < 4) ? 13 : 12;

  i32x16 acc[6];
#pragma unroll
  for (int p = 0; p < 6; ++p)
#pragma unroll
    for (int r = 0; r < 16; ++r) acc[p][r] = 0;

  for (int kc = kc0; kc < kc0 + len; ++kc) {
    i32x4 Af = *(const i32x4*)(Arow + (size_t)kc * 32);
#pragma unroll
    for (int p = 0; p < 6; ++p) {
      i32x4 Bf = *(const i32x4*)(Bbase + (size_t)(p * 196 + kc) * 1024);
      acc[p] = __builtin_amdgcn_mfma_i32_32x32x32_i8(Af, Bf, acc[p], 0, 0, 0);
    }
  }

  long long cc[16];
#pragma unroll
  for (int r = 0; r < 16; ++r) {
    long long v = 0;
#pragma unroll
    for (int p = 0; p < 6; ++p) v += ((long long)acc[p][r]) << (8 * p);
    cc[r] = v;
  }

  if (wid) {
#pragma unroll
    for (int r = 0; r < 16; ++r) red[wid - 1][lane][r] = cc[r];
  }
  __syncthreads();
  if (wid == 0) {
#pragma unroll
    for (int w2 = 0; w2 < 3; ++w2)
#pragma unroll
      for (int r = 0; r < 16; ++r) cc[r] += red[w2][lane][r];
    long long* P = Pbuf + ((size_t)(ks * 256 + Mt * 4 + g)) * 1024 + lane * 16;
#pragma unroll
    for (int r = 0; r < 16; ++r) P[r] = cc[r];
  }
}

// ---------------------------------------------------------------------------
// Dense phase B: sum 4 ks-partials + exchange + i64 LIF scan (R6-verbatim).
// ---------------------------------------------------------------------------
__global__ __launch_bounds__(64) void dense1_scan(
    const long long* __restrict__ Pbuf, const float* __restrict__ bias,
    u16* __restrict__ out) {
  int bidx = blockIdx.x;  // Mt*4+g, 256
  int lane = threadIdx.x;
  int g = bidx & 3, n0 = (bidx >> 2) * 2;

  long long cc[16];
#pragma unroll
  for (int r = 0; r < 16; ++r) cc[r] = 0;
#pragma unroll
  for (int ks = 0; ks < 4; ++ks) {
    const long long* P =
        Pbuf + ((size_t)(ks * 256 + bidx)) * 1024 + lane * 16;
#pragma unroll
    for (int r = 0; r < 16; ++r) cc[r] += P[r];
  }

  int h = lane >> 5, col = lane & 31;
  long long recv[8];
#pragma unroll
  for (int j = 0; j < 8; ++j) {
    long long send = h ? cc[j] : cc[8 + j];
    recv[j] = shfl_xor64(send, 32);
  }
  long long B45 =
      (long long)rint((double)bias[g * 32 + col] * 35184372088832.0);
  long long u = 0;
  u32 mo = 0;
  const long long TH = 1LL << 45;
#pragma unroll
  for (int t = 0; t < TT; ++t) {
    int lo = (t & 3) + 4 * (t >> 3);
    int sel = (t >> 2) & 1;
    long long own = h ? cc[8 + lo] : cc[lo];
    long long ut = (sel ^ h) ? recv[lo] : own;
    ut += B45;
    u += ut;
    if (u >= TH) { mo |= (1u << t); u -= TH; }
  }
  out[(n0 + h) * 128 + g * 32 + col] = (u16)mo;
}

// ---------------------------------------------------------------------------
// Dense 128 -> 10 + spike + rate (R3-verbatim).
// ---------------------------------------------------------------------------
__global__ __launch_bounds__(64) void dense2_out(
    const u16* __restrict__ in, const float* __restrict__ w,
    const float* __restrict__ b, float* __restrict__ out) {
  int idx = blockIdx.x * 64 + threadIdx.x;
  if (idx >= 1280) return;
  int o = idx % 10;
  int n = idx / 10;

  double acc[TT];
  double bv = (double)b[o];
#pragma unroll
  for (int t = 0; t < TT; ++t) acc[t] = bv;

  const u16* inn = in + (size_t)n * 128;
  const float* wo = w + (size_t)o * 128;
  for (int f = 0; f < 128; ++f) {
    u32 m = inn[f];
    double wv = (double)wo[f];
#pragma unroll
    for (int t = 0; t < TT; ++t) acc[t] += ((m >> t) & 1u) ? wv : 0.0;
  }
  u32 mo = scan_spike(acc);
  out[idx] = (float)__popc(mo) * 0.0625f;
}

// ---------------------------------------------------------------------------
extern "C" void kernel_launch(void* const* d_in, const int* in_sizes, int n_in,
                              void* d_out, int out_size, void* d_ws,
                              size_t ws_size, hipStream_t stream) {
  const float* x   = (const float*)d_in[0];
  const float* w1  = (const float*)d_in[1];
  const float* b1  = (const float*)d_in[2];
  const float* w2  = (const float*)d_in[3];
  const float* b2  = (const float*)d_in[4];
  const float* w3  = (const float*)d_in[5];
  const float* b3  = (const float*)d_in[6];
  const float* w4  = (const float*)d_in[7];
  const float* b4  = (const float*)d_in[8];
  const float* w5  = (const float*)d_in[9];
  const float* b5  = (const float*)d_in[10];
  const float* w6  = (const float*)d_in[11];
  const float* b6  = (const float*)d_in[12];
  const float* wf1 = (const float*)d_in[13];
  const float* bf1 = (const float*)d_in[14];
  const float* wf2 = (const float*)d_in[15];
  const float* bf2 = (const float*)d_in[16];
  float* out = (float*)d_out;

  // Workspace layout (byte offsets), max use 47,296,512 B (same as R4-R7).
  char* W = (char*)d_ws;
  u16* s1 = (u16*)(W + 0);               // [128,32,28,28]
  u16* s3 = (u16*)(W + 6422528);
  u16* s4 = (u16*)(W + 12845056);        // [128,32,14,14]
  u16* s5 = (u16*)(W + 14450688);        // [128,16,14,14]
  u16* s6 = (u16*)(W + 15253504);
  u16* s7 = (u16*)(W + 16056320);        // [128,32,14,14]
  u16* s8 = (u16*)(W + 17661952);        // [128,128]
  signed char* Wd2 = (signed char*)(W + 17694720);
  signed char* Wd3 = (signed char*)(W + 17750016);
  signed char* T1c = (signed char*)(W + 17805312);  // 14,745,600 B
  signed char* T2c = (signed char*)(W + 32550912);  // 14,745,600 B
  // Temporal reuse inside the T2c region (conv chain done before these):
  signed char* Wd1 = T2c;                              // 4,816,896 B
  signed char* Wd5 = T2c + 4915200;                    //    36,864 B
  signed char* T5  = T2c + 5242880;                    // 8,392,704 B (w/ pad)
  long long*  Pbuf = (long long*)(T2c + 5242880);      // 8,388,608 B (after T5)
  signed char* T7  = T1c;                              // 12,845,056 B

  const size_t TSZ = (size_t)32 * 30 * 30 * 512;

  prep_digits_frag<<<9, 64, 0, stream>>>(w2, Wd2);
  prep_digits_frag<<<9, 64, 0, stream>>>(w3, Wd3);
  hipMemsetAsync(T1c, 0, TSZ, stream);
  hipMemsetAsync(T2c, 0, TSZ, stream);

  // L1: conv3x3 1->32 + spike (LDS-staged f64)
  conv1_lds<<<3584, 224, 0, stream>>>(x, w1, b1, s1);

  // L2/L3 in 4 n-chunks of 32 (i8 MFMA, 1 tile/wave, pair-collapsed)
  for (int k = 0; k < 4; ++k) {
    expand_masks<<<3136, 256, 0, stream>>>(s1, T1c, k * 32);
    conv_i8<true, false><<<3584, 256, 0, stream>>>(T1c, Wd2, b2, nullptr, T2c,
                                                   nullptr, k * 32);
    conv_i8<false, true><<<3584, 256, 0, stream>>>(T2c, Wd3, b3, s1, nullptr,
                                                   s3, k * 32);
  }

  // L4: avgpool2 + spike
  pool_spike<<<3136, 256, 0, stream>>>(s3, s4);
  // L5: conv1x1 32->16 + spike
  conv1x1_spike<32><<<1568, 256, 0, stream>>>(s4, w4, b4, nullptr, s5, 128, 16,
                                              196);
  // L6: conv3x3 16->16 + spike (i8 MFMA, pair-collapsed)
  hipMemsetAsync(T5, 0, 8392704, stream);
  prep_digits5<<<6, 64, 0, stream>>>(w5, Wd5);
  expand_t5<<<3136, 256, 0, stream>>>(s5, T5);
  conv5_i8<<<3584, 256, 0, stream>>>(T5, Wd5, b5, s6);
  // L7: conv1x1 16->32 + residual(s4) + spike
  conv1x1_spike<16><<<3136, 256, 0, stream>>>(s6, w6, b6, s4, s7, 128, 32, 196);

  // L8: dense 6272->128 (two-phase i8 MFMA)
  expand_t7<<<3136, 256, 0, stream>>>(s7, T7);
  prep_dense_digits<<<1176, 256, 0, stream>>>(wf1, Wd1);
  dense1_part<<<1024, 256, 0, stream>>>(T7, Wd1, Pbuf);
  dense1_scan<<<256, 64, 0, stream>>>(Pbuf, bf1, s8);

  // L9: dense 128->10 + spike + rate
  dense2_out<<<20, 64, 0, stream>>>(s8, wf2, bf2, out);
}

// Round 9
// 664.332 us; speedup vs baseline: 1.1464x; 1.1464x over previous
//
#include <hip/hip_runtime.h>

typedef unsigned short u16;
typedef unsigned int u32;
typedef __attribute__((ext_vector_type(4))) int i32x4;
typedef __attribute__((ext_vector_type(16))) int i32x16;

#define TT 16

// ---------------------------------------------------------------------------
// f64 LIF scan (soft reset, THETA=1). R2..R8: absmax=0.0 => order-free,
// margins >> f64 noise.
// ---------------------------------------------------------------------------
__device__ __forceinline__ u32 scan_spike(const double* acc) {
  double u = 0.0;
  u32 m = 0;
#pragma unroll
  for (int t = 0; t < TT; ++t) {
    u += acc[t];
    if (u >= 1.0) { m |= (1u << t); u -= 1.0; }
  }
  return m;
}

__device__ __forceinline__ long long shfl_xor64(long long v, int m) {
  int lo = __shfl_xor((int)(v & 0xffffffffLL), m);
  int hi = __shfl_xor((int)(v >> 32), m);
  return ((long long)hi << 32) | (u32)lo;
}

// ---------------------------------------------------------------------------
// Layer 1: conv3x3 pad1 Cin=1, LDS-staged, 4 oc/thread (R5-verbatim, proven).
// ---------------------------------------------------------------------------
__global__ __launch_bounds__(224) void conv1_lds(
    const float* __restrict__ x, const float* __restrict__ w,
    const float* __restrict__ b, u16* __restrict__ out) {
  __shared__ float xt[3][30][18];
  __shared__ double wl[32][9];

  int blk = blockIdx.x;
  int y = blk % 28, n = blk / 28;
  int tid = threadIdx.x;

  for (int i = tid; i < 288; i += 224) wl[i / 9][i % 9] = (double)w[i];
  for (int i = tid; i < 3 * 30 * 16; i += 224) {
    int r = i / 480; int rem = i % 480;
    int col = rem / 16; int t = rem % 16;
    int yi = y - 1 + r, xi = col - 1;
    float v = 0.0f;
    if ((unsigned)yi < 28u && (unsigned)xi < 28u)
      v = x[((size_t)(n * 28 + yi) * 28 + xi) * 16 + t];
    xt[r][col][t] = v;
  }
  __syncthreads();

  int xx = tid % 28, ocg = tid / 28, oc0 = ocg * 4;

  double acc[4][TT];
#pragma unroll
  for (int j = 0; j < 4; ++j) {
    double bv = (double)b[oc0 + j];
#pragma unroll
    for (int t = 0; t < TT; ++t) acc[j][t] = bv;
  }

#pragma unroll
  for (int ky = 0; ky < 3; ++ky)
#pragma unroll
    for (int kx = 0; kx < 3; ++kx) {
      int ko = ky * 3 + kx;
      double w0 = wl[oc0][ko], w1 = wl[oc0 + 1][ko];
      double w2 = wl[oc0 + 2][ko], w3 = wl[oc0 + 3][ko];
#pragma unroll
      for (int t = 0; t < TT; ++t) {
        double xv = (double)xt[ky][xx + kx][t];
        acc[0][t] = fma(w0, xv, acc[0][t]);
        acc[1][t] = fma(w1, xv, acc[1][t]);
        acc[2][t] = fma(w2, xv, acc[2][t]);
        acc[3][t] = fma(w3, xv, acc[3][t]);
      }
    }

#pragma unroll
  for (int j = 0; j < 4; ++j) {
    u32 mo = scan_spike(acc[j]);
    out[((size_t)(n * 32 + oc0 + j) * 28 + y) * 28 + xx] = (u16)mo;
  }
}

// ---------------------------------------------------------------------------
// Digit prep in MFMA B-frag order for the 32ch 3x3 convs (R4-verbatim).
// ---------------------------------------------------------------------------
__global__ void prep_digits_frag(const float* __restrict__ w,
                                 signed char* __restrict__ Wd) {
  int tap = blockIdx.x;    // 9
  int lane = threadIdx.x;  // 64
  int oc = lane & 31, kh = lane >> 5;
  for (int j = 0; j < 16; ++j) {
    int c = kh * 16 + j;
    double xv = ldexp((double)w[((size_t)(oc * 32 + c)) * 9 + tap], 45);
    long long X = (long long)rint(xv);
    for (int p = 0; p < 6; ++p) {
      int d = (int)((X + 128) & 255) - 128;
      Wd[((size_t)((p * 9 + tap) * 64 + lane)) * 16 + j] = (signed char)d;
      X = (X - (long long)d) >> 8;
    }
  }
}

// ---------------------------------------------------------------------------
// Expand packed u16 masks -> T[nloc][30][30][16][32] bytes (R4-verbatim).
// ---------------------------------------------------------------------------
__global__ __launch_bounds__(256) void expand_masks(
    const u16* __restrict__ s, signed char* __restrict__ T, int nbase) {
  int site = blockIdx.x * 8 + (threadIdx.x >> 5);
  int gl = threadIdx.x & 31;
  int x = site % 28; int t1 = site / 28;
  int y = t1 % 28;   int nloc = t1 / 28;

  u32 v = (u32)s[(((size_t)(nbase + nloc) * 32 + gl) * 28 + y) * 28 + x];
  const u32 MK[5] = {0x0000FFFFu, 0x00FF00FFu, 0x0F0F0F0Fu,
                     0x33333333u, 0x55555555u};
#pragma unroll
  for (int i = 0; i < 5; ++i) {
    int sh = 16 >> i;
    u32 mk = MK[i];
    u32 p = (u32)__shfl_xor((int)v, sh);
    v = ((gl & sh) == 0) ? ((v & mk) | ((p & mk) << sh))
                         : ((v & ~mk) | ((p & ~mk) >> sh));
  }
  if (gl < 16) {
    u32 dw[8];
#pragma unroll
    for (int d = 0; d < 8; ++d) {
      u32 nib = (v >> (4 * d)) & 0xFu;
      dw[d] = (nib * 0x00204081u) & 0x01010101u;
    }
    signed char* Tp =
        T + (((size_t)nloc * 30 + y + 1) * 30 + (x + 1)) * 512 + gl * 32;
    *(i32x4*)Tp = (i32x4){(int)dw[0], (int)dw[1], (int)dw[2], (int)dw[3]};
    *(i32x4*)(Tp + 16) = (i32x4){(int)dw[4], (int)dw[5], (int)dw[6], (int)dw[7]};
  }
}

// ---------------------------------------------------------------------------
// Integer epilogue for 32x32 i8 MFMA C-layout (R4-verbatim, proven).
// ---------------------------------------------------------------------------
template <bool WRITE_T, bool HAS_RES>
__device__ __forceinline__ void epi_i8(long long (&cc)[16], int h, int oc,
                                       int px_out, int y, int nloc, int n_g,
                                       const float* bias,
                                       const u16* __restrict__ res,
                                       signed char* __restrict__ Tout,
                                       u16* __restrict__ mout) {
  long long recv[8];
#pragma unroll
  for (int j = 0; j < 8; ++j) {
    long long send = h ? cc[j] : cc[8 + j];
    recv[j] = shfl_xor64(send, 32);
  }
  long long B45 = (long long)rint((double)bias[oc] * 35184372088832.0);
  u32 rm = 0;
  if (HAS_RES && px_out < 28)
    rm = res[(((size_t)n_g * 32 + oc) * 28 + y) * 28 + px_out];
  long long u = 0;
  u32 mo = 0;
  const long long TH = 1LL << 45;
#pragma unroll
  for (int t = 0; t < TT; ++t) {
    int lo = (t & 3) + 4 * (t >> 3);
    int sel = (t >> 2) & 1;
    long long own = h ? cc[8 + lo] : cc[lo];
    long long ut = (sel ^ h) ? recv[lo] : own;
    ut += B45 + (((rm >> t) & 1u) ? TH : 0);
    u += ut;
    if (u >= TH) { mo |= (1u << t); u -= TH; }
  }
  if (px_out < 28) {
    if (WRITE_T) {
      signed char* Tp =
          Tout + (((size_t)nloc * 30 + y + 1) * 30 + px_out + 1) * 512 + oc;
#pragma unroll
      for (int t = 0; t < TT; ++t)
        Tp[t * 32] = (signed char)((mo >> t) & 1u);
    } else {
      mout[(((size_t)n_g * 32 + oc) * 28 + y) * 28 + px_out] = (u16)mo;
    }
  }
}

// ---------------------------------------------------------------------------
// conv3x3 32->32 via exact i8 32x32x32 MFMA (R4-verbatim, proven no-spill:
// VGPR=128, 2-px-tile x2 per wave, LDS-staged B, i64 accumulate per p-loop).
// R6-R8 restructures (global-B, 1-tile, pair-collapse) all spilled or
// regressed — this shape is the measured best.
// ---------------------------------------------------------------------------
template <bool WRITE_T, bool HAS_RES>
__global__ __launch_bounds__(256, 2) void conv_i8(
    const signed char* __restrict__ Tin, const signed char* __restrict__ Wd,
    const float* __restrict__ bias, const u16* __restrict__ res,
    signed char* __restrict__ Tout, u16* __restrict__ mout, int nbase) {
  __shared__ signed char WL[6 * 9 * 1024];
  int tid = threadIdx.x;
  for (int j = tid; j < 3456; j += 256)
    ((i32x4*)WL)[j] = ((const i32x4*)Wd)[j];
  __syncthreads();

  int blk = blockIdx.x;
  int xblk = blk & 1; int b2 = blk >> 1;
  int y = b2 % 28;    int nloc = b2 / 28;
  int lane = tid & 63, wid = tid >> 6;
  int h = lane >> 5, rowlane = lane & 31;
  int pxr = rowlane >> 4, tA = rowlane & 15;
  int pxb = xblk * 16 + wid * 4;

  i32x4 A0[9], A1[9];
  const signed char* Tn = Tin + (size_t)nloc * (30 * 30 * 512);
#pragma unroll
  for (int ky = 0; ky < 3; ++ky)
#pragma unroll
    for (int kx = 0; kx < 3; ++kx) {
      int tap = ky * 3 + kx;
      int ypad = y + ky;
      int x0 = pxb + pxr + kx;     if (x0 > 29) x0 = 29;
      int x1 = pxb + 2 + pxr + kx; if (x1 > 29) x1 = 29;
      A0[tap] = *(const i32x4*)(Tn + ((size_t)(ypad * 30 + x0)) * 512 +
                                tA * 32 + h * 16);
      A1[tap] = *(const i32x4*)(Tn + ((size_t)(ypad * 30 + x1)) * 512 +
                                tA * 32 + h * 16);
    }

  long long c0[16], c1[16];
#pragma unroll
  for (int r = 0; r < 16; ++r) { c0[r] = 0; c1[r] = 0; }

#pragma unroll
  for (int p = 0; p < 6; ++p) {
    i32x16 a0 = {0, 0, 0, 0, 0, 0, 0, 0, 0, 0, 0, 0, 0, 0, 0, 0};
    i32x16 a1 = {0, 0, 0, 0, 0, 0, 0, 0, 0, 0, 0, 0, 0, 0, 0, 0};
#pragma unroll
    for (int tap = 0; tap < 9; ++tap) {
      i32x4 Bf = *(const i32x4*)&WL[((size_t)((p * 9 + tap) * 64 + lane)) * 16];
      a0 = __builtin_amdgcn_mfma_i32_32x32x32_i8(A0[tap], Bf, a0, 0, 0, 0);
      a1 = __builtin_amdgcn_mfma_i32_32x32x32_i8(A1[tap], Bf, a1, 0, 0, 0);
    }
#pragma unroll
    for (int r = 0; r < 16; ++r) {
      c0[r] += ((long long)a0[r]) << (8 * p);
      c1[r] += ((long long)a1[r]) << (8 * p);
    }
  }

  int n_g = nbase + nloc;
  int oc = rowlane;
  epi_i8<WRITE_T, HAS_RES>(c0, h, oc, pxb + h, y, nloc, n_g, bias, res, Tout,
                           mout);
  epi_i8<WRITE_T, HAS_RES>(c1, h, oc, pxb + 2 + h, y, nloc, n_g, bias, res,
                           Tout, mout);
}

// ---------------------------------------------------------------------------
// 2x2 average pool + spike (R3-verbatim).
// ---------------------------------------------------------------------------
__global__ __launch_bounds__(256) void pool_spike(
    const u16* __restrict__ in, u16* __restrict__ out) {
  int idx = blockIdx.x * 256 + threadIdx.x;
  const int total = 128 * 32 * 14 * 14;
  if (idx >= total) return;
  int xx = idx % 14; int t1 = idx / 14;
  int yy = t1 % 14;  int t2 = t1 / 14;
  int c  = t2 % 32;  int n  = t2 / 32;

  const u16* base = in + ((size_t)(n * 32 + c) * 28 + yy * 2) * 28 + xx * 2;
  u32 m00 = base[0], m01 = base[1], m10 = base[28], m11 = base[29];

  double acc[TT];
#pragma unroll
  for (int t = 0; t < TT; ++t) {
    u32 s = ((m00 >> t) & 1u) + ((m01 >> t) & 1u) + ((m10 >> t) & 1u) +
            ((m11 >> t) & 1u);
    acc[t] = 0.25 * (double)s;
  }
  out[idx] = (u16)scan_spike(acc);
}

// ---------------------------------------------------------------------------
// conv1x1 on packed binary input + optional residual + spike (R3-verbatim).
// ---------------------------------------------------------------------------
template <int CIN>
__global__ __launch_bounds__(256) void conv1x1_spike(
    const u16* __restrict__ in, const float* __restrict__ w,
    const float* __restrict__ b, const u16* __restrict__ res,
    u16* __restrict__ out, int N, int Cout, int HW) {
  int idx = blockIdx.x * 256 + threadIdx.x;
  int total = N * Cout * HW;
  if (idx >= total) return;
  int p = idx % HW; int t1 = idx / HW;
  int o = t1 % Cout; int n = t1 / Cout;

  double acc[TT];
  double bv = (double)b[o];
#pragma unroll
  for (int t = 0; t < TT; ++t) acc[t] = bv;

  const u16* inp = in + (size_t)n * CIN * HW + p;
  const float* wo = w + (size_t)o * CIN;
#pragma unroll 4
  for (int c = 0; c < CIN; ++c) {
    u32 m = inp[c * HW];
    double wh = 0.5 * (double)wo[c];
#pragma unroll
    for (int t = 0; t < TT; ++t) {
      u32 hi = (m << (30 - t)) & 0x40000000u;
      acc[t] = fma(wh, __hiloint2double((int)hi, 0), acc[t]);
    }
  }
  if (res) {
    u32 m = res[idx];
#pragma unroll
    for (int t = 0; t < TT; ++t) acc[t] += ((m >> t) & 1u) ? 1.0 : 0.0;
  }
  out[idx] = (u16)scan_spike(acc);
}

// ---------------------------------------------------------------------------
// f64 FMA conv3x3 (L6: 16ch 14x14) (R3/R5-verbatim, measured 67 us — the
// i8 conversions of this layer (R6-R8) all spilled and were slower).
// ---------------------------------------------------------------------------
template <int CIN, int COUT, int H, int W>
__global__ __launch_bounds__((COUT / 4) * 64) void conv3x3_fma(
    const u16* __restrict__ in, const float* __restrict__ w,
    const float* __restrict__ b, const u16* __restrict__ res,
    u16* __restrict__ out) {
  constexpr int TX = 16, TY = 4;
  constexpr int TILESX = (W + TX - 1) / TX;
  constexpr int TILESY = (H + TY - 1) / TY;
  constexpr int HALO = 6 * (TX + 2);
  constexpr int BLOCK = (COUT / 4) * 64;
  __shared__ u16 lds[CIN][6][TX + 2];

  int blk = blockIdx.x;
  int tx = blk % TILESX; int t1 = blk / TILESX;
  int ty = t1 % TILESY;  int n  = t1 / TILESY;
  int x0 = tx * TX, y0 = ty * TY;

  int tid = threadIdx.x;

  const u16* inn = in + (size_t)n * CIN * H * W;
  for (int idx = tid; idx < CIN * HALO; idx += BLOCK) {
    int c = idx / HALO; int rem = idx % HALO;
    int r = rem / (TX + 2); int cc = rem % (TX + 2);
    int gy = y0 - 1 + r, gx = x0 - 1 + cc;
    u16 v = 0;
    if ((unsigned)gy < (unsigned)H && (unsigned)gx < (unsigned)W)
      v = inn[(size_t)c * H * W + gy * W + gx];
    lds[c][r][cc] = v;
  }
  __syncthreads();

  int lane = tid & 63;
  int og = __builtin_amdgcn_readfirstlane(tid >> 6);
  int oc0 = og * 4;
  int px = lane & 15, py = lane >> 4;

  double acc[4][TT];
#pragma unroll
  for (int j = 0; j < 4; ++j) {
    double bv = (double)b[oc0 + j];
#pragma unroll
    for (int t = 0; t < TT; ++t) acc[j][t] = bv;
  }

  for (int c = 0; c < CIN; ++c) {
    const float* wc = w + ((size_t)oc0 * CIN + c) * 9;
#pragma unroll
    for (int ky = 0; ky < 3; ++ky) {
#pragma unroll
      for (int kx = 0; kx < 3; ++kx) {
        u32 m = lds[c][py + ky][px + kx];
        int ko = ky * 3 + kx;
        double wh0 = 0.5 * (double)wc[ko];
        double wh1 = 0.5 * (double)wc[CIN * 9 + ko];
        double wh2 = 0.5 * (double)wc[2 * CIN * 9 + ko];
        double wh3 = 0.5 * (double)wc[3 * CIN * 9 + ko];
#pragma unroll
        for (int t = 0; t < TT; ++t) {
          u32 hi = (m << (30 - t)) & 0x40000000u;
          double bf = __hiloint2double((int)hi, 0);
          acc[0][t] = fma(wh0, bf, acc[0][t]);
          acc[1][t] = fma(wh1, bf, acc[1][t]);
          acc[2][t] = fma(wh2, bf, acc[2][t]);
          acc[3][t] = fma(wh3, bf, acc[3][t]);
        }
      }
    }
  }

  int gx = x0 + px, gy = y0 + py;
  if (gx < W && gy < H) {
#pragma unroll
    for (int j = 0; j < 4; ++j) {
      size_t oidx = ((size_t)(n * COUT + oc0 + j) * H + gy) * W + gx;
      double u = 0.0;
      u32 mo = 0;
      if (res) {
        u32 rm = res[oidx];
#pragma unroll
        for (int t = 0; t < TT; ++t) {
          double a = acc[j][t] + (((rm >> t) & 1u) ? 1.0 : 0.0);
          u += a;
          if (u >= 1.0) { mo |= (1u << t); u -= 1.0; }
        }
      } else {
#pragma unroll
        for (int t = 0; t < TT; ++t) {
          u += acc[j][t];
          if (u >= 1.0) { mo |= (1u << t); u -= 1.0; }
        }
      }
      out[oidx] = (u16)mo;
    }
  }
}

// ---------------------------------------------------------------------------
// Expand s7 masks -> T7[n][t][6272] bytes (R5-verbatim).
// ---------------------------------------------------------------------------
__global__ __launch_bounds__(256) void expand_t7(
    const u16* __restrict__ s, signed char* __restrict__ T) {
  int site = blockIdx.x * 8 + (threadIdx.x >> 5);
  int gl = threadIdx.x & 31;
  int fc = site % 196; int n = site / 196;

  u32 v = (u32)s[(size_t)n * 6272 + fc * 32 + gl];
  const u32 MK[5] = {0x0000FFFFu, 0x00FF00FFu, 0x0F0F0F0Fu,
                     0x33333333u, 0x55555555u};
#pragma unroll
  for (int i = 0; i < 5; ++i) {
    int sh = 16 >> i;
    u32 mk = MK[i];
    u32 p = (u32)__shfl_xor((int)v, sh);
    v = ((gl & sh) == 0) ? ((v & mk) | ((p & mk) << sh))
                         : ((v & ~mk) | ((p & ~mk) >> sh));
  }
  if (gl < 16) {
    u32 dw[8];
#pragma unroll
    for (int d = 0; d < 8; ++d) {
      u32 nib = (v >> (4 * d)) & 0xFu;
      dw[d] = (nib * 0x00204081u) & 0x01010101u;
    }
    signed char* Tp = T + ((size_t)n * 16 + gl) * 6272 + fc * 32;
    *(i32x4*)Tp = (i32x4){(int)dw[0], (int)dw[1], (int)dw[2], (int)dw[3]};
    *(i32x4*)(Tp + 16) = (i32x4){(int)dw[4], (int)dw[5], (int)dw[6], (int)dw[7]};
  }
}

// ---------------------------------------------------------------------------
// wf1 digit prep, B-frag order (R5-verbatim).
// ---------------------------------------------------------------------------
__global__ __launch_bounds__(256) void prep_dense_digits(
    const float* __restrict__ w, signed char* __restrict__ Wd) {
  int linear = blockIdx.x * 256 + threadIdx.x;  // < 301056
  int lane = linear & 63;
  int kc = (linear >> 6) % 196;
  int pg = (linear >> 6) / 196;
  int p = pg % 6, g = pg / 6;
  int col = lane & 31, kh = lane >> 5;
  int o = g * 32 + col, fb = kc * 32 + kh * 16;

  alignas(16) signed char dig[16];
#pragma unroll
  for (int j = 0; j < 16; ++j) {
    double xv = (double)w[(size_t)o * 6272 + fb + j] * 35184372088832.0;
    long long X = (long long)rint(xv);
    unsigned long long Y = (unsigned long long)(X + 0x808080808080LL);
    dig[j] = (signed char)(int)(((Y >> (8 * p)) & 255u) - 128);
  }
  *(i32x4*)(Wd + (size_t)linear * 16) = *(const i32x4*)dig;
}

// ---------------------------------------------------------------------------
// Dense 6272->128, phase A: 16-way K-split partial i8 GEMM (R6/R7-verbatim).
// ---------------------------------------------------------------------------
__global__ __launch_bounds__(256) void dense1_part(
    const signed char* __restrict__ T7, const signed char* __restrict__ Wd,
    long long* __restrict__ Pbuf) {
  __shared__ long long red[3][64][16];
  int tid = threadIdx.x, lane = tid & 63, wid = tid >> 6;
  int bidx = blockIdx.x;
  int Mt = bidx & 63;
  int g = (bidx >> 6) & 3;
  int ks = bidx >> 8;
  int n0 = Mt * 2;
  int nl = (lane >> 4) & 1, tA = lane & 15, kh = lane >> 5;

  const signed char* Arow =
      T7 + ((size_t)(n0 + nl) * 16 + tA) * 6272 + kh * 16;
  const signed char* Bbase = Wd + (size_t)g * 6 * 196 * 1024 + lane * 16;

  int slot = ks * 4 + wid;
  int kc0 = slot * 12 + (slot < 4 ? slot : 4);
  int len = (slot < 4) ? 13 : 12;

  i32x16 acc[6];
#pragma unroll
  for (int p = 0; p < 6; ++p)
#pragma unroll
    for (int r = 0; r < 16; ++r) acc[p][r] = 0;

  for (int kc = kc0; kc < kc0 + len; ++kc) {
    i32x4 Af = *(const i32x4*)(Arow + (size_t)kc * 32);
#pragma unroll
    for (int p = 0; p < 6; ++p) {
      i32x4 Bf = *(const i32x4*)(Bbase + (size_t)(p * 196 + kc) * 1024);
      acc[p] = __builtin_amdgcn_mfma_i32_32x32x32_i8(Af, Bf, acc[p], 0, 0, 0);
    }
  }

  long long cc[16];
#pragma unroll
  for (int r = 0; r < 16; ++r) {
    long long v = 0;
#pragma unroll
    for (int p = 0; p < 6; ++p) v += ((long long)acc[p][r]) << (8 * p);
    cc[r] = v;
  }

  if (wid) {
#pragma unroll
    for (int r = 0; r < 16; ++r) red[wid - 1][lane][r] = cc[r];
  }
  __syncthreads();
  if (wid == 0) {
#pragma unroll
    for (int w2 = 0; w2 < 3; ++w2)
#pragma unroll
      for (int r = 0; r < 16; ++r) cc[r] += red[w2][lane][r];
    long long* P = Pbuf + ((size_t)(ks * 256 + Mt * 4 + g)) * 1024 + lane * 16;
#pragma unroll
    for (int r = 0; r < 16; ++r) P[r] = cc[r];
  }
}

// ---------------------------------------------------------------------------
// Dense phase B: sum 4 ks-partials + exchange + i64 LIF scan (R6/R7-verbatim).
// ---------------------------------------------------------------------------
__global__ __launch_bounds__(64) void dense1_scan(
    const long long* __restrict__ Pbuf, const float* __restrict__ bias,
    u16* __restrict__ out) {
  int bidx = blockIdx.x;  // Mt*4+g, 256
  int lane = threadIdx.x;
  int g = bidx & 3, n0 = (bidx >> 2) * 2;

  long long cc[16];
#pragma unroll
  for (int r = 0; r < 16; ++r) cc[r] = 0;
#pragma unroll
  for (int ks = 0; ks < 4; ++ks) {
    const long long* P =
        Pbuf + ((size_t)(ks * 256 + bidx)) * 1024 + lane * 16;
#pragma unroll
    for (int r = 0; r < 16; ++r) cc[r] += P[r];
  }

  int h = lane >> 5, col = lane & 31;
  long long recv[8];
#pragma unroll
  for (int j = 0; j < 8; ++j) {
    long long send = h ? cc[j] : cc[8 + j];
    recv[j] = shfl_xor64(send, 32);
  }
  long long B45 =
      (long long)rint((double)bias[g * 32 + col] * 35184372088832.0);
  long long u = 0;
  u32 mo = 0;
  const long long TH = 1LL << 45;
#pragma unroll
  for (int t = 0; t < TT; ++t) {
    int lo = (t & 3) + 4 * (t >> 3);
    int sel = (t >> 2) & 1;
    long long own = h ? cc[8 + lo] : cc[lo];
    long long ut = (sel ^ h) ? recv[lo] : own;
    ut += B45;
    u += ut;
    if (u >= TH) { mo |= (1u << t); u -= TH; }
  }
  out[(n0 + h) * 128 + g * 32 + col] = (u16)mo;
}

// ---------------------------------------------------------------------------
// Dense 128 -> 10 + spike + rate (R3-verbatim).
// ---------------------------------------------------------------------------
__global__ __launch_bounds__(64) void dense2_out(
    const u16* __restrict__ in, const float* __restrict__ w,
    const float* __restrict__ b, float* __restrict__ out) {
  int idx = blockIdx.x * 64 + threadIdx.x;
  if (idx >= 1280) return;
  int o = idx % 10;
  int n = idx / 10;

  double acc[TT];
  double bv = (double)b[o];
#pragma unroll
  for (int t = 0; t < TT; ++t) acc[t] = bv;

  const u16* inn = in + (size_t)n * 128;
  const float* wo = w + (size_t)o * 128;
  for (int f = 0; f < 128; ++f) {
    u32 m = inn[f];
    double wv = (double)wo[f];
#pragma unroll
    for (int t = 0; t < TT; ++t) acc[t] += ((m >> t) & 1u) ? wv : 0.0;
  }
  u32 mo = scan_spike(acc);
  out[idx] = (float)__popc(mo) * 0.0625f;
}

// ---------------------------------------------------------------------------
extern "C" void kernel_launch(void* const* d_in, const int* in_sizes, int n_in,
                              void* d_out, int out_size, void* d_ws,
                              size_t ws_size, hipStream_t stream) {
  const float* x   = (const float*)d_in[0];
  const float* w1  = (const float*)d_in[1];
  const float* b1  = (const float*)d_in[2];
  const float* w2  = (const float*)d_in[3];
  const float* b2  = (const float*)d_in[4];
  const float* w3  = (const float*)d_in[5];
  const float* b3  = (const float*)d_in[6];
  const float* w4  = (const float*)d_in[7];
  const float* b4  = (const float*)d_in[8];
  const float* w5  = (const float*)d_in[9];
  const float* b5  = (const float*)d_in[10];
  const float* w6  = (const float*)d_in[11];
  const float* b6  = (const float*)d_in[12];
  const float* wf1 = (const float*)d_in[13];
  const float* bf1 = (const float*)d_in[14];
  const float* wf2 = (const float*)d_in[15];
  const float* bf2 = (const float*)d_in[16];
  float* out = (float*)d_out;

  // Workspace layout (byte offsets), max use 47,296,512 B (same as R4-R8).
  char* W = (char*)d_ws;
  u16* s1 = (u16*)(W + 0);               // [128,32,28,28]
  u16* s3 = (u16*)(W + 6422528);
  u16* s4 = (u16*)(W + 12845056);        // [128,32,14,14]
  u16* s5 = (u16*)(W + 14450688);        // [128,16,14,14]
  u16* s6 = (u16*)(W + 15253504);
  u16* s7 = (u16*)(W + 16056320);        // [128,32,14,14]
  u16* s8 = (u16*)(W + 17661952);        // [128,128]
  signed char* Wd2 = (signed char*)(W + 17694720);
  signed char* Wd3 = (signed char*)(W + 17750016);
  signed char* T1c = (signed char*)(W + 17805312);  // 14,745,600 B
  signed char* T2c = (signed char*)(W + 32550912);  // 14,745,600 B
  // Temporal reuse inside the T2c region (conv chain done before these):
  signed char* Wd1 = T2c;                              // 4,816,896 B
  long long*  Pbuf = (long long*)(T2c + 5242880);      // 8,388,608 B
  signed char* T7  = T1c;                              // 12,845,056 B

  const size_t TSZ = (size_t)32 * 30 * 30 * 512;

  prep_digits_frag<<<9, 64, 0, stream>>>(w2, Wd2);
  prep_digits_frag<<<9, 64, 0, stream>>>(w3, Wd3);
  hipMemsetAsync(T1c, 0, TSZ, stream);
  hipMemsetAsync(T2c, 0, TSZ, stream);

  // L1: conv3x3 1->32 + spike (LDS-staged f64)
  conv1_lds<<<3584, 224, 0, stream>>>(x, w1, b1, s1);

  // L2/L3 in 4 n-chunks of 32 (i8 MFMA, R4-proven shape)
  for (int k = 0; k < 4; ++k) {
    expand_masks<<<3136, 256, 0, stream>>>(s1, T1c, k * 32);
    conv_i8<true, false><<<1792, 256, 0, stream>>>(T1c, Wd2, b2, nullptr, T2c,
                                                   nullptr, k * 32);
    conv_i8<false, true><<<1792, 256, 0, stream>>>(T2c, Wd3, b3, s1, nullptr,
                                                   s3, k * 32);
  }

  // L4: avgpool2 + spike
  pool_spike<<<3136, 256, 0, stream>>>(s3, s4);
  // L5: conv1x1 32->16 + spike
  conv1x1_spike<32><<<1568, 256, 0, stream>>>(s4, w4, b4, nullptr, s5, 128, 16,
                                              196);
  // L6: conv3x3 16->16 + spike (f64, R5-proven)
  conv3x3_fma<16, 16, 14, 14><<<512, 256, 0, stream>>>(s5, w5, b5, nullptr, s6);
  // L7: conv1x1 16->32 + residual(s4) + spike
  conv1x1_spike<16><<<3136, 256, 0, stream>>>(s6, w6, b6, s4, s7, 128, 32, 196);

  // L8: dense 6272->128 (two-phase i8 MFMA)
  expand_t7<<<3136, 256, 0, stream>>>(s7, T7);
  prep_dense_digits<<<1176, 256, 0, stream>>>(wf1, Wd1);
  dense1_part<<<1024, 256, 0, stream>>>(T7, Wd1, Pbuf);
  dense1_scan<<<256, 64, 0, stream>>>(Pbuf, bf1, s8);

  // L9: dense 128->10 + spike + rate
  dense2_out<<<20, 64, 0, stream>>>(s8, wf2, bf2, out);
}

// Round 11
// 647.829 us; speedup vs baseline: 1.1756x; 1.0255x over previous
//
#include <hip/hip_runtime.h>

typedef unsigned short u16;
typedef unsigned int u32;
typedef __attribute__((ext_vector_type(4))) int i32x4;
typedef __attribute__((ext_vector_type(16))) int i32x16;

#define TT 16
#define Z16 {0, 0, 0, 0, 0, 0, 0, 0, 0, 0, 0, 0, 0, 0, 0, 0}

// ---------------------------------------------------------------------------
// f64 LIF scan (soft reset, THETA=1). R2..R9: absmax=0.0 => order-free,
// margins >> f64 noise.
// ---------------------------------------------------------------------------
__device__ __forceinline__ u32 scan_spike(const double* acc) {
  double u = 0.0;
  u32 m = 0;
#pragma unroll
  for (int t = 0; t < TT; ++t) {
    u += acc[t];
    if (u >= 1.0) { m |= (1u << t); u -= 1.0; }
  }
  return m;
}

__device__ __forceinline__ long long shfl_xor64(long long v, int m) {
  int lo = __shfl_xor((int)(v & 0xffffffffLL), m);
  int hi = __shfl_xor((int)(v >> 32), m);
  return ((long long)hi << 32) | (u32)lo;
}

// ---------------------------------------------------------------------------
// Layer 1: conv3x3 pad1 Cin=1, LDS-staged, 4 oc/thread (R5-verbatim, proven).
// ---------------------------------------------------------------------------
__global__ __launch_bounds__(224) void conv1_lds(
    const float* __restrict__ x, const float* __restrict__ w,
    const float* __restrict__ b, u16* __restrict__ out) {
  __shared__ float xt[3][30][18];
  __shared__ double wl[32][9];

  int blk = blockIdx.x;
  int y = blk % 28, n = blk / 28;
  int tid = threadIdx.x;

  for (int i = tid; i < 288; i += 224) wl[i / 9][i % 9] = (double)w[i];
  for (int i = tid; i < 3 * 30 * 16; i += 224) {
    int r = i / 480; int rem = i % 480;
    int col = rem / 16; int t = rem % 16;
    int yi = y - 1 + r, xi = col - 1;
    float v = 0.0f;
    if ((unsigned)yi < 28u && (unsigned)xi < 28u)
      v = x[((size_t)(n * 28 + yi) * 28 + xi) * 16 + t];
    xt[r][col][t] = v;
  }
  __syncthreads();

  int xx = tid % 28, ocg = tid / 28, oc0 = ocg * 4;

  double acc[4][TT];
#pragma unroll
  for (int j = 0; j < 4; ++j) {
    double bv = (double)b[oc0 + j];
#pragma unroll
    for (int t = 0; t < TT; ++t) acc[j][t] = bv;
  }

#pragma unroll
  for (int ky = 0; ky < 3; ++ky)
#pragma unroll
    for (int kx = 0; kx < 3; ++kx) {
      int ko = ky * 3 + kx;
      double w0 = wl[oc0][ko], w1 = wl[oc0 + 1][ko];
      double w2 = wl[oc0 + 2][ko], w3 = wl[oc0 + 3][ko];
#pragma unroll
      for (int t = 0; t < TT; ++t) {
        double xv = (double)xt[ky][xx + kx][t];
        acc[0][t] = fma(w0, xv, acc[0][t]);
        acc[1][t] = fma(w1, xv, acc[1][t]);
        acc[2][t] = fma(w2, xv, acc[2][t]);
        acc[3][t] = fma(w3, xv, acc[3][t]);
      }
    }

#pragma unroll
  for (int j = 0; j < 4; ++j) {
    u32 mo = scan_spike(acc[j]);
    out[((size_t)(n * 32 + oc0 + j) * 28 + y) * 28 + xx] = (u16)mo;
  }
}

// ---------------------------------------------------------------------------
// Digit prep in MFMA B-frag order for the 32ch 3x3 convs (R4-verbatim).
// ---------------------------------------------------------------------------
__global__ void prep_digits_frag(const float* __restrict__ w,
                                 signed char* __restrict__ Wd) {
  int tap = blockIdx.x;    // 9
  int lane = threadIdx.x;  // 64
  int oc = lane & 31, kh = lane >> 5;
  for (int j = 0; j < 16; ++j) {
    int c = kh * 16 + j;
    double xv = ldexp((double)w[((size_t)(oc * 32 + c)) * 9 + tap], 45);
    long long X = (long long)rint(xv);
    for (int p = 0; p < 6; ++p) {
      int d = (int)((X + 128) & 255) - 128;
      Wd[((size_t)((p * 9 + tap) * 64 + lane)) * 16 + j] = (signed char)d;
      X = (X - (long long)d) >> 8;
    }
  }
}

// ---------------------------------------------------------------------------
// Zero only the border sites of T1c/T2c (x or y in {0,29}); interiors are
// fully rewritten every chunk (expand_masks / conv_i8<WRITE_T> — proven by
// R4-R9 passing). Replaces 2x14.7 MB memsets with 2x1.9 MB of writes.
// Per buffer: 32 nloc x 116 border sites x 512 B; 16 B per thread.
// ---------------------------------------------------------------------------
__global__ __launch_bounds__(256) void zero_borders(
    signed char* __restrict__ T1, signed char* __restrict__ T2) {
  const int PER = 32 * 116 * 32;  // 16B-chunks per buffer = 118784
  int idx = blockIdx.x * 256 + threadIdx.x;
  int buf = idx >= PER;
  int r = buf ? idx - PER : idx;
  if (r >= PER) return;
  int c16 = r & 31;
  int site = (r >> 5) % 116;
  int nloc = (r >> 5) / 116;
  int y, x;
  if (site < 30) { y = 0; x = site; }
  else if (site < 60) { y = 29; x = site - 30; }
  else if (site < 88) { x = 0; y = site - 60 + 1; }
  else { x = 29; y = site - 88 + 1; }
  signed char* T = buf ? T2 : T1;
  *(i32x4*)(T + (((size_t)nloc * 30 + y) * 30 + x) * 512 + c16 * 16) =
      (i32x4){0, 0, 0, 0};
}

// ---------------------------------------------------------------------------
// Expand packed u16 masks -> T[nloc][30][30][16][32] bytes (R4-verbatim).
// ---------------------------------------------------------------------------
__global__ __launch_bounds__(256) void expand_masks(
    const u16* __restrict__ s, signed char* __restrict__ T, int nbase) {
  int site = blockIdx.x * 8 + (threadIdx.x >> 5);
  int gl = threadIdx.x & 31;
  int x = site % 28; int t1 = site / 28;
  int y = t1 % 28;   int nloc = t1 / 28;

  u32 v = (u32)s[(((size_t)(nbase + nloc) * 32 + gl) * 28 + y) * 28 + x];
  const u32 MK[5] = {0x0000FFFFu, 0x00FF00FFu, 0x0F0F0F0Fu,
                     0x33333333u, 0x55555555u};
#pragma unroll
  for (int i = 0; i < 5; ++i) {
    int sh = 16 >> i;
    u32 mk = MK[i];
    u32 p = (u32)__shfl_xor((int)v, sh);
    v = ((gl & sh) == 0) ? ((v & mk) | ((p & mk) << sh))
                         : ((v & ~mk) | ((p & ~mk) >> sh));
  }
  if (gl < 16) {
    u32 dw[8];
#pragma unroll
    for (int d = 0; d < 8; ++d) {
      u32 nib = (v >> (4 * d)) & 0xFu;
      dw[d] = (nib * 0x00204081u) & 0x01010101u;
    }
    signed char* Tp =
        T + (((size_t)nloc * 30 + y + 1) * 30 + (x + 1)) * 512 + gl * 32;
    *(i32x4*)Tp = (i32x4){(int)dw[0], (int)dw[1], (int)dw[2], (int)dw[3]};
    *(i32x4*)(Tp + 16) = (i32x4){(int)dw[4], (int)dw[5], (int)dw[6], (int)dw[7]};
  }
}

// ---------------------------------------------------------------------------
// Integer epilogue for 32x32 i8 MFMA C-layout (R4-verbatim, proven).
// ---------------------------------------------------------------------------
template <bool WRITE_T, bool HAS_RES>
__device__ __forceinline__ void epi_i8(long long (&cc)[16], int h, int oc,
                                       int px_out, int y, int nloc, int n_g,
                                       const float* bias,
                                       const u16* __restrict__ res,
                                       signed char* __restrict__ Tout,
                                       u16* __restrict__ mout) {
  long long recv[8];
#pragma unroll
  for (int j = 0; j < 8; ++j) {
    long long send = h ? cc[j] : cc[8 + j];
    recv[j] = shfl_xor64(send, 32);
  }
  long long B45 = (long long)rint((double)bias[oc] * 35184372088832.0);
  u32 rm = 0;
  if (HAS_RES && px_out < 28)
    rm = res[(((size_t)n_g * 32 + oc) * 28 + y) * 28 + px_out];
  long long u = 0;
  u32 mo = 0;
  const long long TH = 1LL << 45;
#pragma unroll
  for (int t = 0; t < TT; ++t) {
    int lo = (t & 3) + 4 * (t >> 3);
    int sel = (t >> 2) & 1;
    long long own = h ? cc[8 + lo] : cc[lo];
    long long ut = (sel ^ h) ? recv[lo] : own;
    ut += B45 + (((rm >> t) & 1u) ? TH : 0);
    u += ut;
    if (u >= TH) { mo |= (1u << t); u -= TH; }
  }
  if (px_out < 28) {
    if (WRITE_T) {
      signed char* Tp =
          Tout + (((size_t)nloc * 30 + y + 1) * 30 + px_out + 1) * 512 + oc;
#pragma unroll
      for (int t = 0; t < TT; ++t)
        Tp[t * 32] = (signed char)((mo >> t) & 1u);
    } else {
      mout[(((size_t)n_g * 32 + oc) * 28 + y) * 28 + px_out] = (u16)mo;
    }
  }
}

// ---------------------------------------------------------------------------
// conv3x3 32->32 via exact i8 32x32x32 MFMA. R11 = R4-proven shape (LDS WL,
// 2 tiles/wave, epi_i8) with ONE change: plane-PAIR i32 accumulation.
// Per pair (p,p+1): two MFMA accs, folded c_pair = a_lo + (a_hi<<8)
// (|a_p| <= 127*288 -> |c_pair| < 9.5e6, exact i32; negative-<<8 semantics
// HW-validated by R8 absmax=0.0). i64 built once pre-epilogue:
// cc = c01 + (c23<<16) + (c45<<32) (exact). K-loop 64-bit VALU 768->192 inst.
// ---------------------------------------------------------------------------
template <bool WRITE_T, bool HAS_RES>
__global__ __launch_bounds__(256, 2) void conv_i8(
    const signed char* __restrict__ Tin, const signed char* __restrict__ Wd,
    const float* __restrict__ bias, const u16* __restrict__ res,
    signed char* __restrict__ Tout, u16* __restrict__ mout, int nbase) {
  __shared__ signed char WL[6 * 9 * 1024];
  int tid = threadIdx.x;
  for (int j = tid; j < 3456; j += 256)
    ((i32x4*)WL)[j] = ((const i32x4*)Wd)[j];
  __syncthreads();

  int blk = blockIdx.x;
  int xblk = blk & 1; int b2 = blk >> 1;
  int y = b2 % 28;    int nloc = b2 / 28;
  int lane = tid & 63, wid = tid >> 6;
  int h = lane >> 5, rowlane = lane & 31;
  int pxr = rowlane >> 4, tA = rowlane & 15;
  int pxb = xblk * 16 + wid * 4;

  i32x4 A0[9], A1[9];
  const signed char* Tn = Tin + (size_t)nloc * (30 * 30 * 512);
#pragma unroll
  for (int ky = 0; ky < 3; ++ky)
#pragma unroll
    for (int kx = 0; kx < 3; ++kx) {
      int tap = ky * 3 + kx;
      int ypad = y + ky;
      int x0 = pxb + pxr + kx;     if (x0 > 29) x0 = 29;
      int x1 = pxb + 2 + pxr + kx; if (x1 > 29) x1 = 29;
      A0[tap] = *(const i32x4*)(Tn + ((size_t)(ypad * 30 + x0)) * 512 +
                                tA * 32 + h * 16);
      A1[tap] = *(const i32x4*)(Tn + ((size_t)(ypad * 30 + x1)) * 512 +
                                tA * 32 + h * 16);
    }

  i32x16 cp0[3], cp1[3];
#pragma unroll
  for (int pp = 0; pp < 3; ++pp) {
    i32x16 a0lo = Z16, a0hi = Z16, a1lo = Z16, a1hi = Z16;
#pragma unroll
    for (int tap = 0; tap < 9; ++tap) {
      i32x4 Blo =
          *(const i32x4*)&WL[((size_t)(((2 * pp) * 9 + tap) * 64 + lane)) * 16];
      i32x4 Bhi = *(const i32x4*)&WL[((size_t)(((2 * pp + 1) * 9 + tap) * 64 +
                                               lane)) * 16];
      a0lo = __builtin_amdgcn_mfma_i32_32x32x32_i8(A0[tap], Blo, a0lo, 0, 0, 0);
      a0hi = __builtin_amdgcn_mfma_i32_32x32x32_i8(A0[tap], Bhi, a0hi, 0, 0, 0);
      a1lo = __builtin_amdgcn_mfma_i32_32x32x32_i8(A1[tap], Blo, a1lo, 0, 0, 0);
      a1hi = __builtin_amdgcn_mfma_i32_32x32x32_i8(A1[tap], Bhi, a1hi, 0, 0, 0);
    }
#pragma unroll
    for (int r = 0; r < 16; ++r) {
      cp0[pp][r] = a0lo[r] + (a0hi[r] << 8);
      cp1[pp][r] = a1lo[r] + (a1hi[r] << 8);
    }
  }

  long long c0[16], c1[16];
#pragma unroll
  for (int r = 0; r < 16; ++r) {
    c0[r] = (long long)cp0[0][r] + ((long long)cp0[1][r] << 16) +
            ((long long)cp0[2][r] << 32);
    c1[r] = (long long)cp1[0][r] + ((long long)cp1[1][r] << 16) +
            ((long long)cp1[2][r] << 32);
  }

  int n_g = nbase + nloc;
  int oc = rowlane;
  epi_i8<WRITE_T, HAS_RES>(c0, h, oc, pxb + h, y, nloc, n_g, bias, res, Tout,
                           mout);
  epi_i8<WRITE_T, HAS_RES>(c1, h, oc, pxb + 2 + h, y, nloc, n_g, bias, res,
                           Tout, mout);
}

// ---------------------------------------------------------------------------
// 2x2 average pool + spike (R3-verbatim).
// ---------------------------------------------------------------------------
__global__ __launch_bounds__(256) void pool_spike(
    const u16* __restrict__ in, u16* __restrict__ out) {
  int idx = blockIdx.x * 256 + threadIdx.x;
  const int total = 128 * 32 * 14 * 14;
  if (idx >= total) return;
  int xx = idx % 14; int t1 = idx / 14;
  int yy = t1 % 14;  int t2 = t1 / 14;
  int c  = t2 % 32;  int n  = t2 / 32;

  const u16* base = in + ((size_t)(n * 32 + c) * 28 + yy * 2) * 28 + xx * 2;
  u32 m00 = base[0], m01 = base[1], m10 = base[28], m11 = base[29];

  double acc[TT];
#pragma unroll
  for (int t = 0; t < TT; ++t) {
    u32 s = ((m00 >> t) & 1u) + ((m01 >> t) & 1u) + ((m10 >> t) & 1u) +
            ((m11 >> t) & 1u);
    acc[t] = 0.25 * (double)s;
  }
  out[idx] = (u16)scan_spike(acc);
}

// ---------------------------------------------------------------------------
// conv1x1 on packed binary input + optional residual + spike (R3-verbatim).
// ---------------------------------------------------------------------------
template <int CIN>
__global__ __launch_bounds__(256) void conv1x1_spike(
    const u16* __restrict__ in, const float* __restrict__ w,
    const float* __restrict__ b, const u16* __restrict__ res,
    u16* __restrict__ out, int N, int Cout, int HW) {
  int idx = blockIdx.x * 256 + threadIdx.x;
  int total = N * Cout * HW;
  if (idx >= total) return;
  int p = idx % HW; int t1 = idx / HW;
  int o = t1 % Cout; int n = t1 / Cout;

  double acc[TT];
  double bv = (double)b[o];
#pragma unroll
  for (int t = 0; t < TT; ++t) acc[t] = bv;

  const u16* inp = in + (size_t)n * CIN * HW + p;
  const float* wo = w + (size_t)o * CIN;
#pragma unroll 4
  for (int c = 0; c < CIN; ++c) {
    u32 m = inp[c * HW];
    double wh = 0.5 * (double)wo[c];
#pragma unroll
    for (int t = 0; t < TT; ++t) {
      u32 hi = (m << (30 - t)) & 0x40000000u;
      acc[t] = fma(wh, __hiloint2double((int)hi, 0), acc[t]);
    }
  }
  if (res) {
    u32 m = res[idx];
#pragma unroll
    for (int t = 0; t < TT; ++t) acc[t] += ((m >> t) & 1u) ? 1.0 : 0.0;
  }
  out[idx] = (u16)scan_spike(acc);
}

// ---------------------------------------------------------------------------
// f64 FMA conv3x3 (L6: 16ch 14x14) (R3/R5-verbatim, measured 67 us).
// ---------------------------------------------------------------------------
template <int CIN, int COUT, int H, int W>
__global__ __launch_bounds__((COUT / 4) * 64) void conv3x3_fma(
    const u16* __restrict__ in, const float* __restrict__ w,
    const float* __restrict__ b, const u16* __restrict__ res,
    u16* __restrict__ out) {
  constexpr int TX = 16, TY = 4;
  constexpr int TILESX = (W + TX - 1) / TX;
  constexpr int TILESY = (H + TY - 1) / TY;
  constexpr int HALO = 6 * (TX + 2);
  constexpr int BLOCK = (COUT / 4) * 64;
  __shared__ u16 lds[CIN][6][TX + 2];

  int blk = blockIdx.x;
  int tx = blk % TILESX; int t1 = blk / TILESX;
  int ty = t1 % TILESY;  int n  = t1 / TILESY;
  int x0 = tx * TX, y0 = ty * TY;

  int tid = threadIdx.x;

  const u16* inn = in + (size_t)n * CIN * H * W;
  for (int idx = tid; idx < CIN * HALO; idx += BLOCK) {
    int c = idx / HALO; int rem = idx % HALO;
    int r = rem / (TX + 2); int cc = rem % (TX + 2);
    int gy = y0 - 1 + r, gx = x0 - 1 + cc;
    u16 v = 0;
    if ((unsigned)gy < (unsigned)H && (unsigned)gx < (unsigned)W)
      v = inn[(size_t)c * H * W + gy * W + gx];
    lds[c][r][cc] = v;
  }
  __syncthreads();

  int lane = tid & 63;
  int og = __builtin_amdgcn_readfirstlane(tid >> 6);
  int oc0 = og * 4;
  int px = lane & 15, py = lane >> 4;

  double acc[4][TT];
#pragma unroll
  for (int j = 0; j < 4; ++j) {
    double bv = (double)b[oc0 + j];
#pragma unroll
    for (int t = 0; t < TT; ++t) acc[j][t] = bv;
  }

  for (int c = 0; c < CIN; ++c) {
    const float* wc = w + ((size_t)oc0 * CIN + c) * 9;
#pragma unroll
    for (int ky = 0; ky < 3; ++ky) {
#pragma unroll
      for (int kx = 0; kx < 3; ++kx) {
        u32 m = lds[c][py + ky][px + kx];
        int ko = ky * 3 + kx;
        double wh0 = 0.5 * (double)wc[ko];
        double wh1 = 0.5 * (double)wc[CIN * 9 + ko];
        double wh2 = 0.5 * (double)wc[2 * CIN * 9 + ko];
        double wh3 = 0.5 * (double)wc[3 * CIN * 9 + ko];
#pragma unroll
        for (int t = 0; t < TT; ++t) {
          u32 hi = (m << (30 - t)) & 0x40000000u;
          double bf = __hiloint2double((int)hi, 0);
          acc[0][t] = fma(wh0, bf, acc[0][t]);
          acc[1][t] = fma(wh1, bf, acc[1][t]);
          acc[2][t] = fma(wh2, bf, acc[2][t]);
          acc[3][t] = fma(wh3, bf, acc[3][t]);
        }
      }
    }
  }

  int gx = x0 + px, gy = y0 + py;
  if (gx < W && gy < H) {
#pragma unroll
    for (int j = 0; j < 4; ++j) {
      size_t oidx = ((size_t)(n * COUT + oc0 + j) * H + gy) * W + gx;
      double u = 0.0;
      u32 mo = 0;
      if (res) {
        u32 rm = res[oidx];
#pragma unroll
        for (int t = 0; t < TT; ++t) {
          double a = acc[j][t] + (((rm >> t) & 1u) ? 1.0 : 0.0);
          u += a;
          if (u >= 1.0) { mo |= (1u << t); u -= 1.0; }
        }
      } else {
#pragma unroll
        for (int t = 0; t < TT; ++t) {
          u += acc[j][t];
          if (u >= 1.0) { mo |= (1u << t); u -= 1.0; }
        }
      }
      out[oidx] = (u16)mo;
    }
  }
}

// ---------------------------------------------------------------------------
// Expand s7 masks -> T7[n][t][6272] bytes (R5-verbatim).
// ---------------------------------------------------------------------------
__global__ __launch_bounds__(256) void expand_t7(
    const u16* __restrict__ s, signed char* __restrict__ T) {
  int site = blockIdx.x * 8 + (threadIdx.x >> 5);
  int gl = threadIdx.x & 31;
  int fc = site % 196; int n = site / 196;

  u32 v = (u32)s[(size_t)n * 6272 + fc * 32 + gl];
  const u32 MK[5] = {0x0000FFFFu, 0x00FF00FFu, 0x0F0F0F0Fu,
                     0x33333333u, 0x55555555u};
#pragma unroll
  for (int i = 0; i < 5; ++i) {
    int sh = 16 >> i;
    u32 mk = MK[i];
    u32 p = (u32)__shfl_xor((int)v, sh);
    v = ((gl & sh) == 0) ? ((v & mk) | ((p & mk) << sh))
                         : ((v & ~mk) | ((p & ~mk) >> sh));
  }
  if (gl < 16) {
    u32 dw[8];
#pragma unroll
    for (int d = 0; d < 8; ++d) {
      u32 nib = (v >> (4 * d)) & 0xFu;
      dw[d] = (nib * 0x00204081u) & 0x01010101u;
    }
    signed char* Tp = T + ((size_t)n * 16 + gl) * 6272 + fc * 32;
    *(i32x4*)Tp = (i32x4){(int)dw[0], (int)dw[1], (int)dw[2], (int)dw[3]};
    *(i32x4*)(Tp + 16) = (i32x4){(int)dw[4], (int)dw[5], (int)dw[6], (int)dw[7]};
  }
}

// ---------------------------------------------------------------------------
// wf1 digit prep, B-frag order (R5-verbatim).
// ---------------------------------------------------------------------------
__global__ __launch_bounds__(256) void prep_dense_digits(
    const float* __restrict__ w, signed char* __restrict__ Wd) {
  int linear = blockIdx.x * 256 + threadIdx.x;  // < 301056
  int lane = linear & 63;
  int kc = (linear >> 6) % 196;
  int pg = (linear >> 6) / 196;
  int p = pg % 6, g = pg / 6;
  int col = lane & 31, kh = lane >> 5;
  int o = g * 32 + col, fb = kc * 32 + kh * 16;

  alignas(16) signed char dig[16];
#pragma unroll
  for (int j = 0; j < 16; ++j) {
    double xv = (double)w[(size_t)o * 6272 + fb + j] * 35184372088832.0;
    long long X = (long long)rint(xv);
    unsigned long long Y = (unsigned long long)(X + 0x808080808080LL);
    dig[j] = (signed char)(int)(((Y >> (8 * p)) & 255u) - 128);
  }
  *(i32x4*)(Wd + (size_t)linear * 16) = *(const i32x4*)dig;
}

// ---------------------------------------------------------------------------
// Dense 6272->128, phase A: 16-way K-split partial i8 GEMM (R6/R7-verbatim).
// ---------------------------------------------------------------------------
__global__ __launch_bounds__(256) void dense1_part(
    const signed char* __restrict__ T7, const signed char* __restrict__ Wd,
    long long* __restrict__ Pbuf) {
  __shared__ long long red[3][64][16];
  int tid = threadIdx.x, lane = tid & 63, wid = tid >> 6;
  int bidx = blockIdx.x;
  int Mt = bidx & 63;
  int g = (bidx >> 6) & 3;
  int ks = bidx >> 8;
  int n0 = Mt * 2;
  int nl = (lane >> 4) & 1, tA = lane & 15, kh = lane >> 5;

  const signed char* Arow =
      T7 + ((size_t)(n0 + nl) * 16 + tA) * 6272 + kh * 16;
  const signed char* Bbase = Wd + (size_t)g * 6 * 196 * 1024 + lane * 16;

  int slot = ks * 4 + wid;
  int kc0 = slot * 12 + (slot < 4 ? slot : 4);
  int len = (slot < 4) ? 13 : 12;

  i32x16 acc[6];
#pragma unroll
  for (int p = 0; p < 6; ++p)
#pragma unroll
    for (int r = 0; r < 16; ++r) acc[p][r] = 0;

  for (int kc = kc0; kc < kc0 + len; ++kc) {
    i32x4 Af = *(const i32x4*)(Arow + (size_t)kc * 32);
#pragma unroll
    for (int p = 0; p < 6; ++p) {
      i32x4 Bf = *(const i32x4*)(Bbase + (size_t)(p * 196 + kc) * 1024);
      acc[p] = __builtin_amdgcn_mfma_i32_32x32x32_i8(Af, Bf, acc[p], 0, 0, 0);
    }
  }

  long long cc[16];
#pragma unroll
  for (int r = 0; r < 16; ++r) {
    long long v = 0;
#pragma unroll
    for (int p = 0; p < 6; ++p) v += ((long long)acc[p][r]) << (8 * p);
    cc[r] = v;
  }

  if (wid) {
#pragma unroll
    for (int r = 0; r < 16; ++r) red[wid - 1][lane][r] = cc[r];
  }
  __syncthreads();
  if (wid == 0) {
#pragma unroll
    for (int w2 = 0; w2 < 3; ++w2)
#pragma unroll
      for (int r = 0; r < 16; ++r) cc[r] += red[w2][lane][r];
    long long* P = Pbuf + ((size_t)(ks * 256 + Mt * 4 + g)) * 1024 + lane * 16;
#pragma unroll
    for (int r = 0; r < 16; ++r) P[r] = cc[r];
  }
}

// ---------------------------------------------------------------------------
// Dense phase B: sum 4 ks-partials + exchange + i64 LIF scan (R6/R7-verbatim).
// ---------------------------------------------------------------------------
__global__ __launch_bounds__(64) void dense1_scan(
    const long long* __restrict__ Pbuf, const float* __restrict__ bias,
    u16* __restrict__ out) {
  int bidx = blockIdx.x;  // Mt*4+g, 256
  int lane = threadIdx.x;
  int g = bidx & 3, n0 = (bidx >> 2) * 2;

  long long cc[16];
#pragma unroll
  for (int r = 0; r < 16; ++r) cc[r] = 0;
#pragma unroll
  for (int ks = 0; ks < 4; ++ks) {
    const long long* P =
        Pbuf + ((size_t)(ks * 256 + bidx)) * 1024 + lane * 16;
#pragma unroll
    for (int r = 0; r < 16; ++r) cc[r] += P[r];
  }

  int h = lane >> 5, col = lane & 31;
  long long recv[8];
#pragma unroll
  for (int j = 0; j < 8; ++j) {
    long long send = h ? cc[j] : cc[8 + j];
    recv[j] = shfl_xor64(send, 32);
  }
  long long B45 =
      (long long)rint((double)bias[g * 32 + col] * 35184372088832.0);
  long long u = 0;
  u32 mo = 0;
  const long long TH = 1LL << 45;
#pragma unroll
  for (int t = 0; t < TT; ++t) {
    int lo = (t & 3) + 4 * (t >> 3);
    int sel = (t >> 2) & 1;
    long long own = h ? cc[8 + lo] : cc[lo];
    long long ut = (sel ^ h) ? recv[lo] : own;
    ut += B45;
    u += ut;
    if (u >= TH) { mo |= (1u << t); u -= TH; }
  }
  out[(n0 + h) * 128 + g * 32 + col] = (u16)mo;
}

// ---------------------------------------------------------------------------
// Dense 128 -> 10 + spike + rate (R3-verbatim).
// ---------------------------------------------------------------------------
__global__ __launch_bounds__(64) void dense2_out(
    const u16* __restrict__ in, const float* __restrict__ w,
    const float* __restrict__ b, float* __restrict__ out) {
  int idx = blockIdx.x * 64 + threadIdx.x;
  if (idx >= 1280) return;
  int o = idx % 10;
  int n = idx / 10;

  double acc[TT];
  double bv = (double)b[o];
#pragma unroll
  for (int t = 0; t < TT; ++t) acc[t] = bv;

  const u16* inn = in + (size_t)n * 128;
  const float* wo = w + (size_t)o * 128;
  for (int f = 0; f < 128; ++f) {
    u32 m = inn[f];
    double wv = (double)wo[f];
#pragma unroll
    for (int t = 0; t < TT; ++t) acc[t] += ((m >> t) & 1u) ? wv : 0.0;
  }
  u32 mo = scan_spike(acc);
  out[idx] = (float)__popc(mo) * 0.0625f;
}

// ---------------------------------------------------------------------------
extern "C" void kernel_launch(void* const* d_in, const int* in_sizes, int n_in,
                              void* d_out, int out_size, void* d_ws,
                              size_t ws_size, hipStream_t stream) {
  const float* x   = (const float*)d_in[0];
  const float* w1  = (const float*)d_in[1];
  const float* b1  = (const float*)d_in[2];
  const float* w2  = (const float*)d_in[3];
  const float* b2  = (const float*)d_in[4];
  const float* w3  = (const float*)d_in[5];
  const float* b3  = (const float*)d_in[6];
  const float* w4  = (const float*)d_in[7];
  const float* b4  = (const float*)d_in[8];
  const float* w5  = (const float*)d_in[9];
  const float* b5  = (const float*)d_in[10];
  const float* w6  = (const float*)d_in[11];
  const float* b6  = (const float*)d_in[12];
  const float* wf1 = (const float*)d_in[13];
  const float* bf1 = (const float*)d_in[14];
  const float* wf2 = (const float*)d_in[15];
  const float* bf2 = (const float*)d_in[16];
  float* out = (float*)d_out;

  // Workspace layout (byte offsets), max use 47,296,512 B (same as R4-R9).
  char* W = (char*)d_ws;
  u16* s1 = (u16*)(W + 0);               // [128,32,28,28]
  u16* s3 = (u16*)(W + 6422528);
  u16* s4 = (u16*)(W + 12845056);        // [128,32,14,14]
  u16* s5 = (u16*)(W + 14450688);        // [128,16,14,14]
  u16* s6 = (u16*)(W + 15253504);
  u16* s7 = (u16*)(W + 16056320);        // [128,32,14,14]
  u16* s8 = (u16*)(W + 17661952);        // [128,128]
  signed char* Wd2 = (signed char*)(W + 17694720);
  signed char* Wd3 = (signed char*)(W + 17750016);
  signed char* T1c = (signed char*)(W + 17805312);  // 14,745,600 B
  signed char* T2c = (signed char*)(W + 32550912);  // 14,745,600 B
  // Temporal reuse inside the T2c region (conv chain done before these):
  signed char* Wd1 = T2c;                              // 4,816,896 B
  long long*  Pbuf = (long long*)(T2c + 5242880);      // 8,388,608 B
  signed char* T7  = T1c;                              // 12,845,056 B

  prep_digits_frag<<<9, 64, 0, stream>>>(w2, Wd2);
  prep_digits_frag<<<9, 64, 0, stream>>>(w3, Wd3);
  // Border-only zeroing of T1c/T2c (interiors rewritten every chunk)
  zero_borders<<<928, 256, 0, stream>>>(T1c, T2c);

  // L1: conv3x3 1->32 + spike (LDS-staged f64)
  conv1_lds<<<3584, 224, 0, stream>>>(x, w1, b1, s1);

  // L2/L3 in 4 n-chunks of 32 (i8 MFMA, R4 shape + pair-collapse)
  for (int k = 0; k < 4; ++k) {
    expand_masks<<<3136, 256, 0, stream>>>(s1, T1c, k * 32);
    conv_i8<true, false><<<1792, 256, 0, stream>>>(T1c, Wd2, b2, nullptr, T2c,
                                                   nullptr, k * 32);
    conv_i8<false, true><<<1792, 256, 0, stream>>>(T2c, Wd3, b3, s1, nullptr,
                                                   s3, k * 32);
  }

  // L4: avgpool2 + spike
  pool_spike<<<3136, 256, 0, stream>>>(s3, s4);
  // L5: conv1x1 32->16 + spike
  conv1x1_spike<32><<<1568, 256, 0, stream>>>(s4, w4, b4, nullptr, s5, 128, 16,
                                              196);
  // L6: conv3x3 16->16 + spike (f64, R5-proven)
  conv3x3_fma<16, 16, 14, 14><<<512, 256, 0, stream>>>(s5, w5, b5, nullptr, s6);
  // L7: conv1x1 16->32 + residual(s4) + spike
  conv1x1_spike<16><<<3136, 256, 0, stream>>>(s6, w6, b6, s4, s7, 128, 32, 196);

  // L8: dense 6272->128 (two-phase i8 MFMA)
  expand_t7<<<3136, 256, 0, stream>>>(s7, T7);
  prep_dense_digits<<<1176, 256, 0, stream>>>(wf1, Wd1);
  dense1_part<<<1024, 256, 0, stream>>>(T7, Wd1, Pbuf);
  dense1_scan<<<256, 64, 0, stream>>>(Pbuf, bf1, s8);

  // L9: dense 128->10 + spike + rate
  dense2_out<<<20, 64, 0, stream>>>(s8, wf2, bf2, out);
}

// Round 12
// 639.374 us; speedup vs baseline: 1.1911x; 1.0132x over previous
//
#include <hip/hip_runtime.h>

typedef unsigned short u16;
typedef unsigned int u32;
typedef __attribute__((ext_vector_type(4))) int i32x4;
typedef __attribute__((ext_vector_type(16))) int i32x16;

#define TT 16
#define Z16 {0, 0, 0, 0, 0, 0, 0, 0, 0, 0, 0, 0, 0, 0, 0, 0}

// ---------------------------------------------------------------------------
// f64 LIF scan (soft reset, THETA=1). R2..R11: absmax=0.0 => order-free,
// margins >> f64 noise.
// ---------------------------------------------------------------------------
__device__ __forceinline__ u32 scan_spike(const double* acc) {
  double u = 0.0;
  u32 m = 0;
#pragma unroll
  for (int t = 0; t < TT; ++t) {
    u += acc[t];
    if (u >= 1.0) { m |= (1u << t); u -= 1.0; }
  }
  return m;
}

__device__ __forceinline__ long long shfl_xor64(long long v, int m) {
  int lo = __shfl_xor((int)(v & 0xffffffffLL), m);
  int hi = __shfl_xor((int)(v >> 32), m);
  return ((long long)hi << 32) | (u32)lo;
}

// ---------------------------------------------------------------------------
// Layer 1: conv3x3 pad1 Cin=1, LDS-staged, 4 oc/thread (R5-verbatim, proven).
// ---------------------------------------------------------------------------
__global__ __launch_bounds__(224) void conv1_lds(
    const float* __restrict__ x, const float* __restrict__ w,
    const float* __restrict__ b, u16* __restrict__ out) {
  __shared__ float xt[3][30][18];
  __shared__ double wl[32][9];

  int blk = blockIdx.x;
  int y = blk % 28, n = blk / 28;
  int tid = threadIdx.x;

  for (int i = tid; i < 288; i += 224) wl[i / 9][i % 9] = (double)w[i];
  for (int i = tid; i < 3 * 30 * 16; i += 224) {
    int r = i / 480; int rem = i % 480;
    int col = rem / 16; int t = rem % 16;
    int yi = y - 1 + r, xi = col - 1;
    float v = 0.0f;
    if ((unsigned)yi < 28u && (unsigned)xi < 28u)
      v = x[((size_t)(n * 28 + yi) * 28 + xi) * 16 + t];
    xt[r][col][t] = v;
  }
  __syncthreads();

  int xx = tid % 28, ocg = tid / 28, oc0 = ocg * 4;

  double acc[4][TT];
#pragma unroll
  for (int j = 0; j < 4; ++j) {
    double bv = (double)b[oc0 + j];
#pragma unroll
    for (int t = 0; t < TT; ++t) acc[j][t] = bv;
  }

#pragma unroll
  for (int ky = 0; ky < 3; ++ky)
#pragma unroll
    for (int kx = 0; kx < 3; ++kx) {
      int ko = ky * 3 + kx;
      double w0 = wl[oc0][ko], w1 = wl[oc0 + 1][ko];
      double w2 = wl[oc0 + 2][ko], w3 = wl[oc0 + 3][ko];
#pragma unroll
      for (int t = 0; t < TT; ++t) {
        double xv = (double)xt[ky][xx + kx][t];
        acc[0][t] = fma(w0, xv, acc[0][t]);
        acc[1][t] = fma(w1, xv, acc[1][t]);
        acc[2][t] = fma(w2, xv, acc[2][t]);
        acc[3][t] = fma(w3, xv, acc[3][t]);
      }
    }

#pragma unroll
  for (int j = 0; j < 4; ++j) {
    u32 mo = scan_spike(acc[j]);
    out[((size_t)(n * 32 + oc0 + j) * 28 + y) * 28 + xx] = (u16)mo;
  }
}

// ---------------------------------------------------------------------------
// Digit prep in MFMA B-frag order for the 32ch 3x3 convs (R4-verbatim).
// ---------------------------------------------------------------------------
__global__ void prep_digits_frag(const float* __restrict__ w,
                                 signed char* __restrict__ Wd) {
  int tap = blockIdx.x;    // 9
  int lane = threadIdx.x;  // 64
  int oc = lane & 31, kh = lane >> 5;
  for (int j = 0; j < 16; ++j) {
    int c = kh * 16 + j;
    double xv = ldexp((double)w[((size_t)(oc * 32 + c)) * 9 + tap], 45);
    long long X = (long long)rint(xv);
    for (int p = 0; p < 6; ++p) {
      int d = (int)((X + 128) & 255) - 128;
      Wd[((size_t)((p * 9 + tap) * 64 + lane)) * 16 + j] = (signed char)d;
      X = (X - (long long)d) >> 8;
    }
  }
}

// ---------------------------------------------------------------------------
// L6 digit prep for conv_i8<14,14,16,16>: w5[16][16][3][3] -> same B-frag
// layout as prep_digits_frag but oc>=16 and c>=16 get zero digits
// (N/K zero-padding, exact).
// ---------------------------------------------------------------------------
__global__ void prep_digits5c(const float* __restrict__ w,
                              signed char* __restrict__ Wd) {
  int tap = blockIdx.x;    // 9
  int lane = threadIdx.x;  // 64
  int oc = lane & 31, kh = lane >> 5;
  for (int j = 0; j < 16; ++j) {
    long long X = 0;
    if (oc < 16 && kh == 0) {  // c = j < 16 real
      double xv = ldexp((double)w[((size_t)(oc * 16 + j)) * 9 + tap], 45);
      X = (long long)rint(xv);
    }
    for (int p = 0; p < 6; ++p) {
      int d = (int)((X + 128) & 255) - 128;
      Wd[((size_t)((p * 9 + tap) * 64 + lane)) * 16 + j] = (signed char)d;
      X = (X - (long long)d) >> 8;
    }
  }
}

// ---------------------------------------------------------------------------
// Zero only the border sites of T1c/T2c (x or y in {0,29}); interiors are
// fully rewritten every chunk (proven R4-R11). 2x1.9 MB instead of 29.4 MB.
// ---------------------------------------------------------------------------
__global__ __launch_bounds__(256) void zero_borders(
    signed char* __restrict__ T1, signed char* __restrict__ T2) {
  const int PER = 32 * 116 * 32;  // 16B-chunks per buffer
  int idx = blockIdx.x * 256 + threadIdx.x;
  int buf = idx >= PER;
  int r = buf ? idx - PER : idx;
  if (r >= PER) return;
  int c16 = r & 31;
  int site = (r >> 5) % 116;
  int nloc = (r >> 5) / 116;
  int y, x;
  if (site < 30) { y = 0; x = site; }
  else if (site < 60) { y = 29; x = site - 30; }
  else if (site < 88) { x = 0; y = site - 60 + 1; }
  else { x = 29; y = site - 88 + 1; }
  signed char* T = buf ? T2 : T1;
  *(i32x4*)(T + (((size_t)nloc * 30 + y) * 30 + x) * 512 + c16 * 16) =
      (i32x4){0, 0, 0, 0};
}

// ---------------------------------------------------------------------------
// Expand packed u16 masks -> T[nloc][30][30][16][32] bytes (R4-verbatim).
// ---------------------------------------------------------------------------
__global__ __launch_bounds__(256) void expand_masks(
    const u16* __restrict__ s, signed char* __restrict__ T, int nbase) {
  int site = blockIdx.x * 8 + (threadIdx.x >> 5);
  int gl = threadIdx.x & 31;
  int x = site % 28; int t1 = site / 28;
  int y = t1 % 28;   int nloc = t1 / 28;

  u32 v = (u32)s[(((size_t)(nbase + nloc) * 32 + gl) * 28 + y) * 28 + x];
  const u32 MK[5] = {0x0000FFFFu, 0x00FF00FFu, 0x0F0F0F0Fu,
                     0x33333333u, 0x55555555u};
#pragma unroll
  for (int i = 0; i < 5; ++i) {
    int sh = 16 >> i;
    u32 mk = MK[i];
    u32 p = (u32)__shfl_xor((int)v, sh);
    v = ((gl & sh) == 0) ? ((v & mk) | ((p & mk) << sh))
                         : ((v & ~mk) | ((p & ~mk) >> sh));
  }
  if (gl < 16) {
    u32 dw[8];
#pragma unroll
    for (int d = 0; d < 8; ++d) {
      u32 nib = (v >> (4 * d)) & 0xFu;
      dw[d] = (nib * 0x00204081u) & 0x01010101u;
    }
    signed char* Tp =
        T + (((size_t)nloc * 30 + y + 1) * 30 + (x + 1)) * 512 + gl * 32;
    *(i32x4*)Tp = (i32x4){(int)dw[0], (int)dw[1], (int)dw[2], (int)dw[3]};
    *(i32x4*)(Tp + 16) = (i32x4){(int)dw[4], (int)dw[5], (int)dw[6], (int)dw[7]};
  }
}

// ---------------------------------------------------------------------------
// Expand s5 masks (16 ch) -> T5c[n][16][16][16t][32c] in conv_i8 T-format:
// lower 16 c from the proven 32x32 bit-transpose, upper 16 c zeroed by the
// same store. Borders pre-zeroed by memset.
// ---------------------------------------------------------------------------
__global__ __launch_bounds__(256) void expand_t5c(
    const u16* __restrict__ s, signed char* __restrict__ T) {
  int site = blockIdx.x * 8 + (threadIdx.x >> 5);  // 128*14*14
  int gl = threadIdx.x & 31;
  int x = site % 14; int t1 = site / 14;
  int y = t1 % 14;   int n = t1 / 14;

  u32 v = 0;
  if (gl < 16) v = (u32)s[(((size_t)n * 16 + gl) * 14 + y) * 14 + x];
  const u32 MK[5] = {0x0000FFFFu, 0x00FF00FFu, 0x0F0F0F0Fu,
                     0x33333333u, 0x55555555u};
#pragma unroll
  for (int i = 0; i < 5; ++i) {
    int sh = 16 >> i;
    u32 mk = MK[i];
    u32 p = (u32)__shfl_xor((int)v, sh);
    v = ((gl & sh) == 0) ? ((v & mk) | ((p & mk) << sh))
                         : ((v & ~mk) | ((p & ~mk) >> sh));
  }
  if (gl < 16) {
    u32 dw[4];
#pragma unroll
    for (int d = 0; d < 4; ++d) {
      u32 nib = (v >> (4 * d)) & 0xFu;
      dw[d] = (nib * 0x00204081u) & 0x01010101u;
    }
    signed char* Tp =
        T + ((((size_t)n * 16 + y + 1) * 16 + (x + 1))) * 512 + gl * 32;
    *(i32x4*)Tp = (i32x4){(int)dw[0], (int)dw[1], (int)dw[2], (int)dw[3]};
    *(i32x4*)(Tp + 16) = (i32x4){0, 0, 0, 0};  // upper 16 channels zero
  }
}

// ---------------------------------------------------------------------------
// Integer epilogue for 32x32 i8 MFMA C-layout (R4 algebra, geometry-
// templated; <28,28,30,32> folds to the proven R4 constants).
// ---------------------------------------------------------------------------
template <int H, int W, int PADW, int COUT, bool WRITE_T, bool HAS_RES>
__device__ __forceinline__ void epi_i8(long long (&cc)[16], int h, int oc,
                                       int px_out, int y, int nloc, int n_g,
                                       const float* bias,
                                       const u16* __restrict__ res,
                                       signed char* __restrict__ Tout,
                                       u16* __restrict__ mout) {
  long long recv[8];
#pragma unroll
  for (int j = 0; j < 8; ++j) {
    long long send = h ? cc[j] : cc[8 + j];
    recv[j] = shfl_xor64(send, 32);
  }
  long long B45 = 0;
  if (oc < COUT) B45 = (long long)rint((double)bias[oc] * 35184372088832.0);
  u32 rm = 0;
  if (HAS_RES && px_out < W)
    rm = res[(((size_t)n_g * COUT + oc) * H + y) * W + px_out];
  long long u = 0;
  u32 mo = 0;
  const long long TH = 1LL << 45;
#pragma unroll
  for (int t = 0; t < TT; ++t) {
    int lo = (t & 3) + 4 * (t >> 3);
    int sel = (t >> 2) & 1;
    long long own = h ? cc[8 + lo] : cc[lo];
    long long ut = (sel ^ h) ? recv[lo] : own;
    ut += B45 + (((rm >> t) & 1u) ? TH : 0);
    u += ut;
    if (u >= TH) { mo |= (1u << t); u -= TH; }
  }
  if (px_out < W && oc < COUT) {
    if (WRITE_T) {
      signed char* Tp =
          Tout + (((size_t)nloc * PADW + y + 1) * PADW + px_out + 1) * 512 + oc;
#pragma unroll
      for (int t = 0; t < TT; ++t)
        Tp[t * 32] = (signed char)((mo >> t) & 1u);
    } else {
      mout[(((size_t)n_g * COUT + oc) * H + y) * W + px_out] = (u16)mo;
    }
  }
}

// ---------------------------------------------------------------------------
// conv3x3 via exact i8 32x32x32 MFMA. R11-proven shape (LDS WL, 2 tiles/wave,
// plane-pair i32 accumulation, epi_i8), geometry-templated:
//   <28,28,30,32> = L2/L3 (codegen-identical to R11's proven instance)
//   <14,14,16,16> = L6 (zero-padded channels; clamps fold to no-ops)
// ---------------------------------------------------------------------------
template <int H, int W, int PADW, int COUT, bool WRITE_T, bool HAS_RES>
__global__ __launch_bounds__(256, 2) void conv_i8(
    const signed char* __restrict__ Tin, const signed char* __restrict__ Wd,
    const float* __restrict__ bias, const u16* __restrict__ res,
    signed char* __restrict__ Tout, u16* __restrict__ mout, int nbase) {
  constexpr int TILESX = (W + 15) / 16;
  __shared__ signed char WL[6 * 9 * 1024];
  int tid = threadIdx.x;
  for (int j = tid; j < 3456; j += 256)
    ((i32x4*)WL)[j] = ((const i32x4*)Wd)[j];
  __syncthreads();

  int blk = blockIdx.x;
  int xblk = blk % TILESX; int b2 = blk / TILESX;
  int y = b2 % H;          int nloc = b2 / H;
  int lane = tid & 63, wid = tid >> 6;
  int h = lane >> 5, rowlane = lane & 31;
  int pxr = rowlane >> 4, tA = rowlane & 15;
  int pxb = xblk * 16 + wid * 4;

  i32x4 A0[9], A1[9];
  const signed char* Tn = Tin + (size_t)nloc * (PADW * PADW * 512);
#pragma unroll
  for (int ky = 0; ky < 3; ++ky)
#pragma unroll
    for (int kx = 0; kx < 3; ++kx) {
      int tap = ky * 3 + kx;
      int ypad = y + ky;
      int x0 = pxb + pxr + kx;     if (x0 > PADW - 1) x0 = PADW - 1;
      int x1 = pxb + 2 + pxr + kx; if (x1 > PADW - 1) x1 = PADW - 1;
      A0[tap] = *(const i32x4*)(Tn + ((size_t)(ypad * PADW + x0)) * 512 +
                                tA * 32 + h * 16);
      A1[tap] = *(const i32x4*)(Tn + ((size_t)(ypad * PADW + x1)) * 512 +
                                tA * 32 + h * 16);
    }

  i32x16 cp0[3], cp1[3];
#pragma unroll
  for (int pp = 0; pp < 3; ++pp) {
    i32x16 a0lo = Z16, a0hi = Z16, a1lo = Z16, a1hi = Z16;
#pragma unroll
    for (int tap = 0; tap < 9; ++tap) {
      i32x4 Blo =
          *(const i32x4*)&WL[((size_t)(((2 * pp) * 9 + tap) * 64 + lane)) * 16];
      i32x4 Bhi = *(const i32x4*)&WL[((size_t)(((2 * pp + 1) * 9 + tap) * 64 +
                                               lane)) * 16];
      a0lo = __builtin_amdgcn_mfma_i32_32x32x32_i8(A0[tap], Blo, a0lo, 0, 0, 0);
      a0hi = __builtin_amdgcn_mfma_i32_32x32x32_i8(A0[tap], Bhi, a0hi, 0, 0, 0);
      a1lo = __builtin_amdgcn_mfma_i32_32x32x32_i8(A1[tap], Blo, a1lo, 0, 0, 0);
      a1hi = __builtin_amdgcn_mfma_i32_32x32x32_i8(A1[tap], Bhi, a1hi, 0, 0, 0);
    }
#pragma unroll
    for (int r = 0; r < 16; ++r) {
      cp0[pp][r] = a0lo[r] + (a0hi[r] << 8);
      cp1[pp][r] = a1lo[r] + (a1hi[r] << 8);
    }
  }

  long long c0[16], c1[16];
#pragma unroll
  for (int r = 0; r < 16; ++r) {
    c0[r] = (long long)cp0[0][r] + ((long long)cp0[1][r] << 16) +
            ((long long)cp0[2][r] << 32);
    c1[r] = (long long)cp1[0][r] + ((long long)cp1[1][r] << 16) +
            ((long long)cp1[2][r] << 32);
  }

  int n_g = nbase + nloc;
  int oc = rowlane;
  epi_i8<H, W, PADW, COUT, WRITE_T, HAS_RES>(c0, h, oc, pxb + h, y, nloc, n_g,
                                             bias, res, Tout, mout);
  epi_i8<H, W, PADW, COUT, WRITE_T, HAS_RES>(c1, h, oc, pxb + 2 + h, y, nloc,
                                             n_g, bias, res, Tout, mout);
}

// ---------------------------------------------------------------------------
// 2x2 average pool + spike (R3-verbatim).
// ---------------------------------------------------------------------------
__global__ __launch_bounds__(256) void pool_spike(
    const u16* __restrict__ in, u16* __restrict__ out) {
  int idx = blockIdx.x * 256 + threadIdx.x;
  const int total = 128 * 32 * 14 * 14;
  if (idx >= total) return;
  int xx = idx % 14; int t1 = idx / 14;
  int yy = t1 % 14;  int t2 = t1 / 14;
  int c  = t2 % 32;  int n  = t2 / 32;

  const u16* base = in + ((size_t)(n * 32 + c) * 28 + yy * 2) * 28 + xx * 2;
  u32 m00 = base[0], m01 = base[1], m10 = base[28], m11 = base[29];

  double acc[TT];
#pragma unroll
  for (int t = 0; t < TT; ++t) {
    u32 s = ((m00 >> t) & 1u) + ((m01 >> t) & 1u) + ((m10 >> t) & 1u) +
            ((m11 >> t) & 1u);
    acc[t] = 0.25 * (double)s;
  }
  out[idx] = (u16)scan_spike(acc);
}

// ---------------------------------------------------------------------------
// conv1x1 on packed binary input + optional residual + spike (R3-verbatim).
// ---------------------------------------------------------------------------
template <int CIN>
__global__ __launch_bounds__(256) void conv1x1_spike(
    const u16* __restrict__ in, const float* __restrict__ w,
    const float* __restrict__ b, const u16* __restrict__ res,
    u16* __restrict__ out, int N, int Cout, int HW) {
  int idx = blockIdx.x * 256 + threadIdx.x;
  int total = N * Cout * HW;
  if (idx >= total) return;
  int p = idx % HW; int t1 = idx / HW;
  int o = t1 % Cout; int n = t1 / Cout;

  double acc[TT];
  double bv = (double)b[o];
#pragma unroll
  for (int t = 0; t < TT; ++t) acc[t] = bv;

  const u16* inp = in + (size_t)n * CIN * HW + p;
  const float* wo = w + (size_t)o * CIN;
#pragma unroll 4
  for (int c = 0; c < CIN; ++c) {
    u32 m = inp[c * HW];
    double wh = 0.5 * (double)wo[c];
#pragma unroll
    for (int t = 0; t < TT; ++t) {
      u32 hi = (m << (30 - t)) & 0x40000000u;
      acc[t] = fma(wh, __hiloint2double((int)hi, 0), acc[t]);
    }
  }
  if (res) {
    u32 m = res[idx];
#pragma unroll
    for (int t = 0; t < TT; ++t) acc[t] += ((m >> t) & 1u) ? 1.0 : 0.0;
  }
  out[idx] = (u16)scan_spike(acc);
}

// ---------------------------------------------------------------------------
// Expand s7 masks -> T7[n][t][6272] bytes (R5-verbatim).
// ---------------------------------------------------------------------------
__global__ __launch_bounds__(256) void expand_t7(
    const u16* __restrict__ s, signed char* __restrict__ T) {
  int site = blockIdx.x * 8 + (threadIdx.x >> 5);
  int gl = threadIdx.x & 31;
  int fc = site % 196; int n = site / 196;

  u32 v = (u32)s[(size_t)n * 6272 + fc * 32 + gl];
  const u32 MK[5] = {0x0000FFFFu, 0x00FF00FFu, 0x0F0F0F0Fu,
                     0x33333333u, 0x55555555u};
#pragma unroll
  for (int i = 0; i < 5; ++i) {
    int sh = 16 >> i;
    u32 mk = MK[i];
    u32 p = (u32)__shfl_xor((int)v, sh);
    v = ((gl & sh) == 0) ? ((v & mk) | ((p & mk) << sh))
                         : ((v & ~mk) | ((p & ~mk) >> sh));
  }
  if (gl < 16) {
    u32 dw[8];
#pragma unroll
    for (int d = 0; d < 8; ++d) {
      u32 nib = (v >> (4 * d)) & 0xFu;
      dw[d] = (nib * 0x00204081u) & 0x01010101u;
    }
    signed char* Tp = T + ((size_t)n * 16 + gl) * 6272 + fc * 32;
    *(i32x4*)Tp = (i32x4){(int)dw[0], (int)dw[1], (int)dw[2], (int)dw[3]};
    *(i32x4*)(Tp + 16) = (i32x4){(int)dw[4], (int)dw[5], (int)dw[6], (int)dw[7]};
  }
}

// ---------------------------------------------------------------------------
// wf1 digit prep, B-frag order (R5-verbatim).
// ---------------------------------------------------------------------------
__global__ __launch_bounds__(256) void prep_dense_digits(
    const float* __restrict__ w, signed char* __restrict__ Wd) {
  int linear = blockIdx.x * 256 + threadIdx.x;  // < 301056
  int lane = linear & 63;
  int kc = (linear >> 6) % 196;
  int pg = (linear >> 6) / 196;
  int p = pg % 6, g = pg / 6;
  int col = lane & 31, kh = lane >> 5;
  int o = g * 32 + col, fb = kc * 32 + kh * 16;

  alignas(16) signed char dig[16];
#pragma unroll
  for (int j = 0; j < 16; ++j) {
    double xv = (double)w[(size_t)o * 6272 + fb + j] * 35184372088832.0;
    long long X = (long long)rint(xv);
    unsigned long long Y = (unsigned long long)(X + 0x808080808080LL);
    dig[j] = (signed char)(int)(((Y >> (8 * p)) & 255u) - 128);
  }
  *(i32x4*)(Wd + (size_t)linear * 16) = *(const i32x4*)dig;
}

// ---------------------------------------------------------------------------
// Dense 6272->128, phase A: 16-way K-split partial i8 GEMM (R6/R7-verbatim).
// ---------------------------------------------------------------------------
__global__ __launch_bounds__(256) void dense1_part(
    const signed char* __restrict__ T7, const signed char* __restrict__ Wd,
    long long* __restrict__ Pbuf) {
  __shared__ long long red[3][64][16];
  int tid = threadIdx.x, lane = tid & 63, wid = tid >> 6;
  int bidx = blockIdx.x;
  int Mt = bidx & 63;
  int g = (bidx >> 6) & 3;
  int ks = bidx >> 8;
  int n0 = Mt * 2;
  int nl = (lane >> 4) & 1, tA = lane & 15, kh = lane >> 5;

  const signed char* Arow =
      T7 + ((size_t)(n0 + nl) * 16 + tA) * 6272 + kh * 16;
  const signed char* Bbase = Wd + (size_t)g * 6 * 196 * 1024 + lane * 16;

  int slot = ks * 4 + wid;
  int kc0 = slot * 12 + (slot < 4 ? slot : 4);
  int len = (slot < 4) ? 13 : 12;

  i32x16 acc[6];
#pragma unroll
  for (int p = 0; p < 6; ++p)
#pragma unroll
    for (int r = 0; r < 16; ++r) acc[p][r] = 0;

  for (int kc = kc0; kc < kc0 + len; ++kc) {
    i32x4 Af = *(const i32x4*)(Arow + (size_t)kc * 32);
#pragma unroll
    for (int p = 0; p < 6; ++p) {
      i32x4 Bf = *(const i32x4*)(Bbase + (size_t)(p * 196 + kc) * 1024);
      acc[p] = __builtin_amdgcn_mfma_i32_32x32x32_i8(Af, Bf, acc[p], 0, 0, 0);
    }
  }

  long long cc[16];
#pragma unroll
  for (int r = 0; r < 16; ++r) {
    long long v = 0;
#pragma unroll
    for (int p = 0; p < 6; ++p) v += ((long long)acc[p][r]) << (8 * p);
    cc[r] = v;
  }

  if (wid) {
#pragma unroll
    for (int r = 0; r < 16; ++r) red[wid - 1][lane][r] = cc[r];
  }
  __syncthreads();
  if (wid == 0) {
#pragma unroll
    for (int w2 = 0; w2 < 3; ++w2)
#pragma unroll
      for (int r = 0; r < 16; ++r) cc[r] += red[w2][lane][r];
    long long* P = Pbuf + ((size_t)(ks * 256 + Mt * 4 + g)) * 1024 + lane * 16;
#pragma unroll
    for (int r = 0; r < 16; ++r) P[r] = cc[r];
  }
}

// ---------------------------------------------------------------------------
// Dense phase B: sum 4 ks-partials + exchange + i64 LIF scan (R6/R7-verbatim).
// ---------------------------------------------------------------------------
__global__ __launch_bounds__(64) void dense1_scan(
    const long long* __restrict__ Pbuf, const float* __restrict__ bias,
    u16* __restrict__ out) {
  int bidx = blockIdx.x;  // Mt*4+g, 256
  int lane = threadIdx.x;
  int g = bidx & 3, n0 = (bidx >> 2) * 2;

  long long cc[16];
#pragma unroll
  for (int r = 0; r < 16; ++r) cc[r] = 0;
#pragma unroll
  for (int ks = 0; ks < 4; ++ks) {
    const long long* P =
        Pbuf + ((size_t)(ks * 256 + bidx)) * 1024 + lane * 16;
#pragma unroll
    for (int r = 0; r < 16; ++r) cc[r] += P[r];
  }

  int h = lane >> 5, col = lane & 31;
  long long recv[8];
#pragma unroll
  for (int j = 0; j < 8; ++j) {
    long long send = h ? cc[j] : cc[8 + j];
    recv[j] = shfl_xor64(send, 32);
  }
  long long B45 =
      (long long)rint((double)bias[g * 32 + col] * 35184372088832.0);
  long long u = 0;
  u32 mo = 0;
  const long long TH = 1LL << 45;
#pragma unroll
  for (int t = 0; t < TT; ++t) {
    int lo = (t & 3) + 4 * (t >> 3);
    int sel = (t >> 2) & 1;
    long long own = h ? cc[8 + lo] : cc[lo];
    long long ut = (sel ^ h) ? recv[lo] : own;
    ut += B45;
    u += ut;
    if (u >= TH) { mo |= (1u << t); u -= TH; }
  }
  out[(n0 + h) * 128 + g * 32 + col] = (u16)mo;
}

// ---------------------------------------------------------------------------
// Dense 128 -> 10 + spike + rate (R3-verbatim).
// ---------------------------------------------------------------------------
__global__ __launch_bounds__(64) void dense2_out(
    const u16* __restrict__ in, const float* __restrict__ w,
    const float* __restrict__ b, float* __restrict__ out) {
  int idx = blockIdx.x * 64 + threadIdx.x;
  if (idx >= 1280) return;
  int o = idx % 10;
  int n = idx / 10;

  double acc[TT];
  double bv = (double)b[o];
#pragma unroll
  for (int t = 0; t < TT; ++t) acc[t] = bv;

  const u16* inn = in + (size_t)n * 128;
  const float* wo = w + (size_t)o * 128;
  for (int f = 0; f < 128; ++f) {
    u32 m = inn[f];
    double wv = (double)wo[f];
#pragma unroll
    for (int t = 0; t < TT; ++t) acc[t] += ((m >> t) & 1u) ? wv : 0.0;
  }
  u32 mo = scan_spike(acc);
  out[idx] = (float)__popc(mo) * 0.0625f;
}

// ---------------------------------------------------------------------------
extern "C" void kernel_launch(void* const* d_in, const int* in_sizes, int n_in,
                              void* d_out, int out_size, void* d_ws,
                              size_t ws_size, hipStream_t stream) {
  const float* x   = (const float*)d_in[0];
  const float* w1  = (const float*)d_in[1];
  const float* b1  = (const float*)d_in[2];
  const float* w2  = (const float*)d_in[3];
  const float* b2  = (const float*)d_in[4];
  const float* w3  = (const float*)d_in[5];
  const float* b3  = (const float*)d_in[6];
  const float* w4  = (const float*)d_in[7];
  const float* b4  = (const float*)d_in[8];
  const float* w5  = (const float*)d_in[9];
  const float* b5  = (const float*)d_in[10];
  const float* w6  = (const float*)d_in[11];
  const float* b6  = (const float*)d_in[12];
  const float* wf1 = (const float*)d_in[13];
  const float* bf1 = (const float*)d_in[14];
  const float* wf2 = (const float*)d_in[15];
  const float* bf2 = (const float*)d_in[16];
  float* out = (float*)d_out;

  // Workspace layout (byte offsets), max use 47,296,512 B (same as R4-R11).
  char* W = (char*)d_ws;
  u16* s1 = (u16*)(W + 0);               // [128,32,28,28]
  u16* s3 = (u16*)(W + 6422528);
  u16* s4 = (u16*)(W + 12845056);        // [128,32,14,14]
  u16* s5 = (u16*)(W + 14450688);        // [128,16,14,14]
  u16* s6 = (u16*)(W + 15253504);
  u16* s7 = (u16*)(W + 16056320);        // [128,32,14,14]
  u16* s8 = (u16*)(W + 17661952);        // [128,128]
  signed char* Wd2 = (signed char*)(W + 17694720);
  signed char* Wd3 = (signed char*)(W + 17750016);
  signed char* T1c = (signed char*)(W + 17805312);  // 14,745,600 B
  signed char* T2c = (signed char*)(W + 32550912);  // 14,745,600 B
  // Temporal reuse (all strictly ordered on the single stream):
  //  - L6: T5c spans T1c..+16.8MB (into Wd1's future region; both dead then),
  //        Wd5c sits above it.
  //  - L8: T7 = T1c, Wd1 = T2c head, Pbuf = T2c+5.24MB (T5c/Wd5c dead).
  signed char* T5c  = T1c;                             // 16,777,216 B
  signed char* Wd5c = (signed char*)(W + 34582528);    //     55,296 B
  signed char* Wd1 = T2c;                              //  4,816,896 B
  long long*  Pbuf = (long long*)(T2c + 5242880);      //  8,388,608 B
  signed char* T7  = T1c;                              // 12,845,056 B

  prep_digits_frag<<<9, 64, 0, stream>>>(w2, Wd2);
  prep_digits_frag<<<9, 64, 0, stream>>>(w3, Wd3);
  // Border-only zeroing of T1c/T2c (interiors rewritten every chunk)
  zero_borders<<<928, 256, 0, stream>>>(T1c, T2c);

  // L1: conv3x3 1->32 + spike (LDS-staged f64)
  conv1_lds<<<3584, 224, 0, stream>>>(x, w1, b1, s1);

  // L2/L3 in 4 n-chunks of 32 (i8 MFMA, proven shape + pair-collapse)
  for (int k = 0; k < 4; ++k) {
    expand_masks<<<3136, 256, 0, stream>>>(s1, T1c, k * 32);
    conv_i8<28, 28, 30, 32, true, false><<<1792, 256, 0, stream>>>(
        T1c, Wd2, b2, nullptr, T2c, nullptr, k * 32);
    conv_i8<28, 28, 30, 32, false, true><<<1792, 256, 0, stream>>>(
        T2c, Wd3, b3, s1, nullptr, s3, k * 32);
  }

  // L4: avgpool2 + spike
  pool_spike<<<3136, 256, 0, stream>>>(s3, s4);
  // L5: conv1x1 32->16 + spike
  conv1x1_spike<32><<<1568, 256, 0, stream>>>(s4, w4, b4, nullptr, s5, 128, 16,
                                              196);
  // L6: conv3x3 16->16 + spike via the proven conv_i8 shape, zero-padded
  // channels (full batch, 1792 blocks)
  hipMemsetAsync(T5c, 0, 16777216, stream);
  prep_digits5c<<<9, 64, 0, stream>>>(w5, Wd5c);
  expand_t5c<<<3136, 256, 0, stream>>>(s5, T5c);
  conv_i8<14, 14, 16, 16, false, false><<<1792, 256, 0, stream>>>(
      T5c, Wd5c, b5, nullptr, nullptr, s6, 0);
  // L7: conv1x1 16->32 + residual(s4) + spike
  conv1x1_spike<16><<<3136, 256, 0, stream>>>(s6, w6, b6, s4, s7, 128, 32, 196);

  // L8: dense 6272->128 (two-phase i8 MFMA)
  expand_t7<<<3136, 256, 0, stream>>>(s7, T7);
  prep_dense_digits<<<1176, 256, 0, stream>>>(wf1, Wd1);
  dense1_part<<<1024, 256, 0, stream>>>(T7, Wd1, Pbuf);
  dense1_scan<<<256, 64, 0, stream>>>(Pbuf, bf1, s8);

  // L9: dense 128->10 + spike + rate
  dense2_out<<<20, 64, 0, stream>>>(s8, wf2, bf2, out);
}